// Round 3
// baseline (330.567 us; speedup 1.0000x reference)
//
#include <hip/hip_runtime.h>

typedef unsigned short u16;
typedef unsigned int u32;
typedef float f32x4 __attribute__((ext_vector_type(4)));
typedef __bf16 bf16x8 __attribute__((ext_vector_type(8)));
typedef u32 u32x4 __attribute__((ext_vector_type(4)));

#define LOG2E 1.44269504088896340736f

static __device__ __forceinline__ u16 f2bf(float f){ u32 u=__builtin_bit_cast(u32,f); u32 r=u+0x7fffu+((u>>16)&1u); return (u16)(r>>16); }
static __device__ __forceinline__ float bf2f(u16 h){ u32 u=((u32)h)<<16; return __builtin_bit_cast(float,u); }
static __device__ __forceinline__ f32x4 mfma16(u32x4 a,u32x4 b,f32x4 c){
  return __builtin_amdgcn_mfma_f32_16x16x32_bf16(__builtin_bit_cast(bf16x8,a),__builtin_bit_cast(bf16x8,b),c,0,0,0);
}
static __device__ __forceinline__ u32x4 ldfrag(const u32* p){
  uint2 a=*(const uint2*)p; uint2 b=*(const uint2*)(p+2);
  u32x4 r; r.x=a.x; r.y=a.y; r.z=b.x; r.w=b.y; return r;
}
static __device__ __forceinline__ void stlds(u32* d, uint4 v){
  *(uint2*)d = make_uint2(v.x,v.y); *(uint2*)(d+2) = make_uint2(v.z,v.w);
}

// ---------------- group-norm statistics: per-group sum / sumsq ----------------
// grid 128 (16 groups x 8 slices), block 256. group = 64ch * 4096 = 262144 f32.
__global__ __launch_bounds__(256) void k_stats(const float* __restrict__ x, const float* __restrict__ c,
                                               float* __restrict__ stats){
  const int g=blockIdx.x>>3, slice=blockIdx.x&7;
  const float* src=(g<8?x:c)+(size_t)(g&7)*262144+(size_t)slice*32768;
  const float4* p=(const float4*)src;
  const int t=threadIdx.x;
  float s1=0.f,s2=0.f;
  for(int i=0;i<32;i++){
    float4 v=p[t+i*256];
    s1+=v.x+v.y+v.z+v.w;
    s2+=v.x*v.x+v.y*v.y+v.z*v.z+v.w*v.w;
  }
  #pragma unroll
  for(int m=1;m<64;m<<=1){ s1+=__shfl_xor(s1,m,64); s2+=__shfl_xor(s2,m,64); }
  __shared__ float r1[4],r2[4];
  const int lane=t&63,w=t>>6;
  if(lane==0){ r1[w]=s1; r2[w]=s2; }
  __syncthreads();
  if(t==0){
    atomicAdd(&stats[2*g],   r1[0]+r1[1]+r1[2]+r1[3]);
    atomicAdd(&stats[2*g+1], r2[0]+r2[1]+r2[2]+r2[3]);
  }
}

// ------------- fold group-norm affine into GEMM weights + biases --------------
// rows 0..511: q_w (x-norm), 512..1535: kv_w (ctx-norm), 1536..2047: copy proj_b.
// W'[r][ci] = W[r][ci]*alpha[ci]; bias'[r] = b[r] + sum_ci W[r][ci]*beta[ci].
__global__ __launch_bounds__(256) void k_prep(const float* __restrict__ qw,const float* __restrict__ qb,
    const float* __restrict__ kvw,const float* __restrict__ kvb,
    const float* __restrict__ nw,const float* __restrict__ nb,
    const float* __restrict__ ncw,const float* __restrict__ ncb,
    const float* __restrict__ pb,const float* __restrict__ stats,
    u16* __restrict__ Wall,float* __restrict__ biasAll){
  const int lane=threadIdx.x&63, w=threadIdx.x>>6;
  const int r=blockIdx.x*4+w;
  if(r>=1536){ if(lane==0) biasAll[r]=pb[r-1536]; return; }
  const bool isq = r<512;
  const float* Wsrc = isq ? qw+(size_t)r*512 : kvw+(size_t)(r-512)*512;
  const float* anw = isq ? nw : ncw;
  const float* anb = isq ? nb : ncb;
  const int gbase = isq ? 0 : 8;
  const float bin = isq ? qb[r] : kvb[r-512];
  const int ci0=lane*8;
  float4 wa=*(const float4*)(Wsrc+ci0);
  float4 wb=*(const float4*)(Wsrc+ci0+4);
  float wf[8]={wa.x,wa.y,wa.z,wa.w,wb.x,wb.y,wb.z,wb.w};
  float bp=0.f; u16 hb[8];
  #pragma unroll
  for(int j=0;j<8;j++){
    int ci=ci0+j;
    int g=gbase+(ci>>6);
    float mean=stats[2*g]*(1.f/262144.f);
    float var =stats[2*g+1]*(1.f/262144.f)-mean*mean;
    float rstd=rsqrtf(var+1e-5f);
    float alv=anw[ci]*rstd;
    float bev=anb[ci]-mean*alv;
    bp+=wf[j]*bev;
    hb[j]=f2bf(wf[j]*alv);
  }
  uint4 ov;
  ov.x=(u32)hb[0]|((u32)hb[1]<<16);
  ov.y=(u32)hb[2]|((u32)hb[3]<<16);
  ov.z=(u32)hb[4]|((u32)hb[5]<<16);
  ov.w=(u32)hb[6]|((u32)hb[7]<<16);
  *(uint4*)(Wall+(size_t)r*512+ci0)=ov;
  #pragma unroll
  for(int m=1;m<64;m<<=1) bp+=__shfl_xor(bp,m,64);
  if(lane==0) biasAll[r]=bin+bp;
}

// ---------------- BT-form GEMM: C[m][n] = sum_k A[m][k]*B[n][k], K=512 --------
// BM=64, BN=128, BK=32; 4 waves, wave tile 32x64.
// AMODE 0: A bf16 [M][K] row-major          (V: Wall)
// AMODE 1: A fp32 [K][4096], transpose-stage (Q/K: x/ctx; m-index = spatial)
// AMODE 2: A fp32 [M][K] row-major          (proj: proj_w)
// BMODE 0: B bf16 [N][K] row-major          (Q/K: Wall)
// BMODE 1: B bf16 head layout [k/64][4096][64] (proj: Oh)
// BMODE 2: B fp32 [K][4096], transpose-stage (V: ctx; n-index = spatial)
// SMODE 0: bf16 head-layout store (m=s, n=co), bias[n], *scale  (Q / K)
// SMODE 1: bf16 plain store out[m*4096+n], bias[m]              (V)
// SMODE 2: fp32 store out[m*4096+n] + bias[m] + fp32 resid      (proj)
template<int AMODE,int BMODE,int SMODE>
__global__ __launch_bounds__(256) void k_gemm(const void* __restrict__ Av,const void* __restrict__ Bv,
    const float* __restrict__ bias,const float* __restrict__ residf,
    void* __restrict__ outv,float scale){
  __shared__ __align__(16) u32 As[64*18];   // [64 m][32 k], row stride 36 u16
  __shared__ __align__(16) u32 Bs[128*18];  // [128 n][32 k]
  const int t=threadIdx.x, lane=t&63, w=t>>6;
  const int wm=w&1, wn=w>>1, quad=lane>>4, l15=lane&15;
  const int m0=blockIdx.y*64, n0=blockIdx.x*128;
  f32x4 acc[2][4];
  #pragma unroll
  for(int i=0;i<2;i++)
    #pragma unroll
    for(int j=0;j<4;j++){ acc[i][j].x=0.f; acc[i][j].y=0.f; acc[i][j].z=0.f; acc[i][j].w=0.f; }
  const int arow=t>>2, akc=(t&3)*8;
  const int cl=t>>3, s8=(t&7)*8;
  for(int kk=0;kk<512;kk+=32){
    __syncthreads();
    // ---- stage A ----
    if(AMODE==0){
      const u16* A=(const u16*)Av;
      uint4 v=*(const uint4*)(A+(size_t)(m0+arow)*512+kk+akc);
      stlds(&As[arow*18+(akc>>1)],v);
    }else if(AMODE==1){
      const float* A=(const float*)Av;
      float4 va=*(const float4*)(A+(size_t)(kk+cl)*4096+m0+s8);
      float4 vb=*(const float4*)(A+(size_t)(kk+cl)*4096+m0+s8+4);
      float f[8]={va.x,va.y,va.z,va.w,vb.x,vb.y,vb.z,vb.w};
      u16* As16=(u16*)As;
      #pragma unroll
      for(int j=0;j<8;j++) As16[(s8+j)*36+cl]=f2bf(f[j]);
    }else{
      const float* A=(const float*)Av;
      float4 va=*(const float4*)(A+(size_t)(m0+arow)*512+kk+akc);
      float4 vb=*(const float4*)(A+(size_t)(m0+arow)*512+kk+akc+4);
      uint4 ov;
      ov.x=(u32)f2bf(va.x)|((u32)f2bf(va.y)<<16);
      ov.y=(u32)f2bf(va.z)|((u32)f2bf(va.w)<<16);
      ov.z=(u32)f2bf(vb.x)|((u32)f2bf(vb.y)<<16);
      ov.w=(u32)f2bf(vb.z)|((u32)f2bf(vb.w)<<16);
      stlds(&As[arow*18+(akc>>1)],ov);
    }
    // ---- stage B ----
    #pragma unroll
    for(int rep=0;rep<2;rep++){
      if(BMODE==2){
        const float* B=(const float*)Bv;
        float4 va=*(const float4*)(B+(size_t)(kk+cl)*4096+n0+rep*64+s8);
        float4 vb=*(const float4*)(B+(size_t)(kk+cl)*4096+n0+rep*64+s8+4);
        float f[8]={va.x,va.y,va.z,va.w,vb.x,vb.y,vb.z,vb.w};
        u16* Bs16=(u16*)Bs;
        #pragma unroll
        for(int j=0;j<8;j++) Bs16[(rep*64+s8+j)*36+cl]=f2bf(f[j]);
      }else{
        const u16* B=(const u16*)Bv;
        int row=arow+rep*64;
        const u16* src;
        if(BMODE==1) src = B + ((size_t)((kk>>6)*4096 + n0+row))*64 + (kk&63) + akc;
        else         src = B + (size_t)(n0+row)*512 + kk + akc;
        uint4 v=*(const uint4*)src;
        stlds(&Bs[row*18+(akc>>1)],v);
      }
    }
    __syncthreads();
    u32x4 af[2], bfr[4];
    #pragma unroll
    for(int mt=0;mt<2;mt++) af[mt]=ldfrag(&As[(wm*32+mt*16+l15)*18+quad*4]);
    #pragma unroll
    for(int nt=0;nt<4;nt++) bfr[nt]=ldfrag(&Bs[(wn*64+nt*16+l15)*18+quad*4]);
    #pragma unroll
    for(int mt=0;mt<2;mt++)
      #pragma unroll
      for(int nt=0;nt<4;nt++) acc[mt][nt]=mfma16(af[mt],bfr[nt],acc[mt][nt]);
  }
  #pragma unroll
  for(int mt=0;mt<2;mt++)
    #pragma unroll
    for(int nt=0;nt<4;nt++){
      const int n = n0 + wn*64 + nt*16 + l15;
      if(SMODE==0){
        u16* out=(u16*)outv;
        const float bn = bias[n];
        const size_t base = ((size_t)((n>>6)*4096))*64 + (size_t)(n&63);
        #pragma unroll
        for(int r=0;r<4;r++){
          int m = m0 + wm*32 + mt*16 + quad*4 + r;
          out[base + (size_t)m*64] = f2bf((acc[mt][nt][r]+bn)*scale);
        }
      } else if(SMODE==1){
        u16* out=(u16*)outv;
        #pragma unroll
        for(int r=0;r<4;r++){
          int m = m0 + wm*32 + mt*16 + quad*4 + r;
          out[(size_t)m*4096+n] = f2bf(acc[mt][nt][r] + bias[m]);
        }
      } else {
        float* out=(float*)outv;
        #pragma unroll
        for(int r=0;r<4;r++){
          int m = m0 + wm*32 + mt*16 + quad*4 + r;
          out[(size_t)m*4096+n] = acc[mt][nt][r] + bias[m] + residf[(size_t)m*4096+n];
        }
      }
    }
}

// ---------------- flash attention: per (head, 64-row Q tile) ------------------
// Q,K head layout [h][s][64]; V plain [h*64+cc][s]; O head layout [h][s][64].
// Q is pre-scaled by 0.125*log2e -> softmax in exp2 domain. All bf16 internal.
__global__ __launch_bounds__(256) void k_attn(const u16* __restrict__ Qh,const u16* __restrict__ Kh,
                                              const u16* __restrict__ Vp,u16* __restrict__ Oh){
  __shared__ __align__(16) u32 Qs[64*34];
  __shared__ __align__(16) u32 Ks[64*34];
  __shared__ __align__(16) u32 Vs[64*34];
  __shared__ __align__(16) u32 Ps[4][16*34];
  const int t=threadIdx.x, lane=t&63, w=t>>6, quad=lane>>4, l15=lane&15;
  const int h=blockIdx.y, s0=blockIdx.x*64;
  const int srow=t>>2, sc=(t&3)*16;
  { const u16* p = Qh + ((size_t)(h*4096+s0+srow))*64 + sc;
    stlds(&Qs[srow*34+(sc>>1)],   *(const uint4*)p);
    stlds(&Qs[srow*34+(sc>>1)+4], *(const uint4*)(p+8)); }
  __syncthreads();
  u32x4 qf[2];
  #pragma unroll
  for(int ks=0;ks<2;ks++) qf[ks]=ldfrag(&Qs[(w*16+l15)*34+ks*16+quad*4]);
  float mrun[4], lrun[4]; f32x4 oacc[4];
  #pragma unroll
  for(int r=0;r<4;r++){ mrun[r]=-1e30f; lrun[r]=0.f; }
  #pragma unroll
  for(int nt=0;nt<4;nt++){ oacc[nt].x=0.f; oacc[nt].y=0.f; oacc[nt].z=0.f; oacc[nt].w=0.f; }

  for(int t0=0;t0<4096;t0+=64){
    __syncthreads();
    { const u16* p = Kh + ((size_t)(h*4096+t0+srow))*64 + sc;
      stlds(&Ks[srow*34+(sc>>1)],   *(const uint4*)p);
      stlds(&Ks[srow*34+(sc>>1)+4], *(const uint4*)(p+8));
      const u16* q = Vp + (size_t)(h*64+srow)*4096 + t0 + sc;
      stlds(&Vs[srow*34+(sc>>1)],   *(const uint4*)q);
      stlds(&Vs[srow*34+(sc>>1)+4], *(const uint4*)(q+8)); }
    __syncthreads();
    f32x4 sv[4];
    #pragma unroll
    for(int nt=0;nt<4;nt++){
      f32x4 z; z.x=0.f; z.y=0.f; z.z=0.f; z.w=0.f;
      u32x4 k0=ldfrag(&Ks[(nt*16+l15)*34+quad*4]);
      u32x4 k1=ldfrag(&Ks[(nt*16+l15)*34+16+quad*4]);
      z=mfma16(qf[0],k0,z);
      sv[nt]=mfma16(qf[1],k1,z);
    }
    float al[4];
    #pragma unroll
    for(int r=0;r<4;r++){
      float mx=fmaxf(fmaxf(sv[0][r],sv[1][r]),fmaxf(sv[2][r],sv[3][r]));
      #pragma unroll
      for(int m=1;m<16;m<<=1) mx=fmaxf(mx,__shfl_xor(mx,m,64));
      float mn=fmaxf(mrun[r],mx);
      al[r]=exp2f(mrun[r]-mn);
      float rs=0.f;
      #pragma unroll
      for(int nt=0;nt<4;nt++){ float p=exp2f(sv[nt][r]-mn); sv[nt][r]=p; rs+=p; }
      #pragma unroll
      for(int m=1;m<16;m<<=1) rs+=__shfl_xor(rs,m,64);
      lrun[r]=lrun[r]*al[r]+rs; mrun[r]=mn;
    }
    u16* pw_=(u16*)Ps[w];
    #pragma unroll
    for(int nt=0;nt<4;nt++)
      #pragma unroll
      for(int r=0;r<4;r++){
        pw_[(quad*4+r)*68 + nt*16 + l15]=f2bf(sv[nt][r]);
        oacc[nt][r]*=al[r];
      }
    #pragma unroll
    for(int ks=0;ks<2;ks++){
      u32x4 pf=ldfrag(&Ps[w][l15*34+ks*16+quad*4]);
      #pragma unroll
      for(int nt=0;nt<4;nt++){
        u32x4 vf=ldfrag(&Vs[(nt*16+l15)*34+ks*16+quad*4]);
        oacc[nt]=mfma16(pf,vf,oacc[nt]);
      }
    }
  }
  #pragma unroll
  for(int r=0;r<4;r++){ float inv=1.f/fmaxf(lrun[r],1e-30f);
    #pragma unroll
    for(int nt=0;nt<4;nt++) oacc[nt][r]*=inv; }
  #pragma unroll
  for(int nt=0;nt<4;nt++)
    #pragma unroll
    for(int r=0;r<4;r++)
      Oh[((size_t)(h*4096+s0+w*16+quad*4+r))*64 + nt*16 + l15]=f2bf(oacc[nt][r]);
}

// ------------------------------- launcher -------------------------------------
extern "C" void kernel_launch(void* const* d_in, const int* in_sizes, int n_in,
                              void* d_out, int out_size, void* d_ws, size_t ws_size,
                              hipStream_t stream){
  (void)in_sizes; (void)n_in; (void)out_size; (void)ws_size;
  const float* x  =(const float*)d_in[0];
  const float* ctx=(const float*)d_in[1];
  const float* nw =(const float*)d_in[2];
  const float* nb =(const float*)d_in[3];
  const float* ncw=(const float*)d_in[4];
  const float* ncb=(const float*)d_in[5];
  const float* qw =(const float*)d_in[6];
  const float* qb =(const float*)d_in[7];
  const float* kvw=(const float*)d_in[8];
  const float* kvb=(const float*)d_in[9];
  const float* pw =(const float*)d_in[10];
  const float* pb =(const float*)d_in[11];
  float* out=(float*)d_out;
  char* ws=(char*)d_ws;
  float* stats  =(float*)ws;                 // [0, 128)
  float* biasAll=(float*)(ws+256);           // [256, 8448): 2048 f32 (q,k,v,proj)
  u16* Wall=(u16*)(ws+16384);                // [16384, 1589248): 1536x512 bf16
  u16* Qh  =(u16*)(ws+1589248);              // [8][4096][64] bf16 (4 MB)
  u16* Kh  =(u16*)(ws+5783552);              // [8][4096][64]
  u16* Vp  =(u16*)(ws+9977856);              // [512][4096]
  u16* Oh  =(u16*)(ws+14172160);             // [8][4096][64], ends 18366464

  hipMemsetAsync(stats,0,128,stream);
  k_stats<<<dim3(128),dim3(256),0,stream>>>(x,ctx,stats);
  k_prep<<<dim3(512),dim3(256),0,stream>>>(qw,qb,kvw,kvb,nw,nb,ncw,ncb,pb,stats,Wall,biasAll);
  // Q: Q[s][co] = sum_c x[c][s] * Wq'[co][c], scaled by 0.125*log2e
  k_gemm<1,0,0><<<dim3(4,64),dim3(256),0,stream>>>(x,   Wall,          biasAll,      nullptr, Qh, 0.125f*LOG2E);
  // K: K[s][co] = sum_c ctx[c][s] * Wk'[co][c]
  k_gemm<1,0,0><<<dim3(4,64),dim3(256),0,stream>>>(ctx, Wall+512*512,  biasAll+512,  nullptr, Kh, 1.f);
  // V: V[co][s] = sum_c Wv'[co][c] * ctx[c][s]   (plain [c][s] layout)
  k_gemm<0,2,1><<<dim3(32,8),dim3(256),0,stream>>>(Wall+1024*512, ctx, biasAll+1024, nullptr, Vp, 1.f);
  k_attn<<<dim3(64,8),dim3(256),0,stream>>>(Qh,Kh,Vp,Oh);
  // proj + residual: out[c][s] = proj_w * O + proj_b + x   (fp32 out)
  k_gemm<2,1,2><<<dim3(32,8),dim3(256),0,stream>>>(pw, Oh, biasAll+1536, x, out, 1.f);
}

// Round 4
// 240.352 us; speedup vs baseline: 1.3753x; 1.3753x over previous
//
#include <hip/hip_runtime.h>

typedef unsigned short u16;
typedef unsigned int u32;
typedef float f32x4 __attribute__((ext_vector_type(4)));
typedef __bf16 bf16x8 __attribute__((ext_vector_type(8)));
typedef u32 u32x4 __attribute__((ext_vector_type(4)));

#define LOG2E 1.44269504088896340736f

static __device__ __forceinline__ u16 f2bf(float f){ u32 u=__builtin_bit_cast(u32,f); u32 r=u+0x7fffu+((u>>16)&1u); return (u16)(r>>16); }
static __device__ __forceinline__ f32x4 mfma16(u32x4 a,u32x4 b,f32x4 c){
  return __builtin_amdgcn_mfma_f32_16x16x32_bf16(__builtin_bit_cast(bf16x8,a),__builtin_bit_cast(bf16x8,b),c,0,0,0);
}
static __device__ __forceinline__ u32x4 ldfrag(const u32* p){
  uint2 a=*(const uint2*)p; uint2 b=*(const uint2*)(p+2);
  u32x4 r; r.x=a.x; r.y=a.y; r.z=b.x; r.w=b.y; return r;
}
static __device__ __forceinline__ void stlds(u32* d, uint4 v){
  *(uint2*)d = make_uint2(v.x,v.y); *(uint2*)(d+2) = make_uint2(v.z,v.w);
}
static __device__ __forceinline__ uint4 pack8(float4 a,float4 b){
  uint4 o;
  o.x=(u32)f2bf(a.x)|((u32)f2bf(a.y)<<16);
  o.y=(u32)f2bf(a.z)|((u32)f2bf(a.w)<<16);
  o.z=(u32)f2bf(b.x)|((u32)f2bf(b.y)<<16);
  o.w=(u32)f2bf(b.z)|((u32)f2bf(b.w)<<16);
  return o;
}

// ---------------- group-norm statistics: per-group sum / sumsq ----------------
__global__ __launch_bounds__(256) void k_stats(const float* __restrict__ x, const float* __restrict__ c,
                                               float* __restrict__ stats){
  const int g=blockIdx.x>>3, slice=blockIdx.x&7;
  const float* src=(g<8?x:c)+(size_t)(g&7)*262144+(size_t)slice*32768;
  const float4* p=(const float4*)src;
  const int t=threadIdx.x;
  float s1=0.f,s2=0.f;
  for(int i=0;i<32;i++){
    float4 v=p[t+i*256];
    s1+=v.x+v.y+v.z+v.w;
    s2+=v.x*v.x+v.y*v.y+v.z*v.z+v.w*v.w;
  }
  #pragma unroll
  for(int m=1;m<64;m<<=1){ s1+=__shfl_xor(s1,m,64); s2+=__shfl_xor(s2,m,64); }
  __shared__ float r1[4],r2[4];
  const int lane=t&63,w=t>>6;
  if(lane==0){ r1[w]=s1; r2[w]=s2; }
  __syncthreads();
  if(t==0){
    atomicAdd(&stats[2*g],   r1[0]+r1[1]+r1[2]+r1[3]);
    atomicAdd(&stats[2*g+1], r2[0]+r2[1]+r2[2]+r2[3]);
  }
}

// ------------- fold group-norm affine into GEMM weights + biases --------------
__global__ __launch_bounds__(256) void k_prep(const float* __restrict__ qw,const float* __restrict__ qb,
    const float* __restrict__ kvw,const float* __restrict__ kvb,
    const float* __restrict__ nw,const float* __restrict__ nb,
    const float* __restrict__ ncw,const float* __restrict__ ncb,
    const float* __restrict__ pb,const float* __restrict__ stats,
    u16* __restrict__ Wall,float* __restrict__ biasAll){
  const int lane=threadIdx.x&63, w=threadIdx.x>>6;
  const int r=blockIdx.x*4+w;
  if(r>=1536){ if(lane==0) biasAll[r]=pb[r-1536]; return; }
  const bool isq = r<512;
  const float* Wsrc = isq ? qw+(size_t)r*512 : kvw+(size_t)(r-512)*512;
  const float* anw = isq ? nw : ncw;
  const float* anb = isq ? nb : ncb;
  const int gbase = isq ? 0 : 8;
  const float bin = isq ? qb[r] : kvb[r-512];
  const int ci0=lane*8;
  float4 wa=*(const float4*)(Wsrc+ci0);
  float4 wb=*(const float4*)(Wsrc+ci0+4);
  float wf[8]={wa.x,wa.y,wa.z,wa.w,wb.x,wb.y,wb.z,wb.w};
  float bp=0.f; u16 hb[8];
  #pragma unroll
  for(int j=0;j<8;j++){
    int ci=ci0+j;
    int g=gbase+(ci>>6);
    float mean=stats[2*g]*(1.f/262144.f);
    float var =stats[2*g+1]*(1.f/262144.f)-mean*mean;
    float rstd=rsqrtf(var+1e-5f);
    float alv=anw[ci]*rstd;
    float bev=anb[ci]-mean*alv;
    bp+=wf[j]*bev;
    hb[j]=f2bf(wf[j]*alv);
  }
  uint4 ov;
  ov.x=(u32)hb[0]|((u32)hb[1]<<16);
  ov.y=(u32)hb[2]|((u32)hb[3]<<16);
  ov.z=(u32)hb[4]|((u32)hb[5]<<16);
  ov.w=(u32)hb[6]|((u32)hb[7]<<16);
  *(uint4*)(Wall+(size_t)r*512+ci0)=ov;
  #pragma unroll
  for(int m=1;m<64;m<<=1) bp+=__shfl_xor(bp,m,64);
  if(lane==0) biasAll[r]=bin+bp;
}

// ---------------- BT-form GEMM: C[m][n] = sum_k A[m][k]*B[n][k], K=512 --------
// BM=64, BN=128, BK=32; double-buffered LDS; 4 waves, wave tile 32x64.
// AMODE 0: A bf16 [M][K] row-major          (V: Wall)
// AMODE 1: A fp32 [K][4096], transpose-stage (Q/K: x/ctx)
// AMODE 2: A fp32 [M][K] row-major          (proj: proj_w)
// BMODE 0: B bf16 [N][K] row-major          (Q/K: Wall)
// BMODE 1: B bf16 head layout [k/64][4096][64] (proj: Oh)
// BMODE 2: B fp32 [K][4096], transpose-stage (V: ctx)
// SMODE 0: bf16 head-layout store, bias[n], *scale  (Q / K)
// SMODE 1: bf16 plain store out[m*4096+n], bias[m]  (V)
// SMODE 2: fp32 store + bias[m] + fp32 resid        (proj)
// ZM: blockIdx.z selects (Av,out1,scale1,bias) vs (Av2,out2,scale2,bias+512), B += z*512*512
template<int AMODE,int BMODE,int SMODE,int ZM>
__global__ __launch_bounds__(256) void k_gemm(const void* __restrict__ Av,const void* __restrict__ Av2,
    const void* __restrict__ Bv,const float* __restrict__ biasAll,const float* __restrict__ residf,
    void* __restrict__ out1,void* __restrict__ out2,float scale1,float scale2){
  __shared__ __align__(16) u32 As[2][64*18];
  __shared__ __align__(16) u32 Bs[2][128*18];
  const int t=threadIdx.x, lane=t&63, w=t>>6;
  const int wm=w&1, wn=w>>1, quad=lane>>4, l15=lane&15;
  const int m0=blockIdx.y*64, n0=blockIdx.x*128;
  const int z = ZM ? blockIdx.z : 0;
  const void* Aptr = (ZM && z) ? Av2 : Av;
  const u16* Bu = (const u16*)Bv + (BMODE==0 ? (size_t)z*512*512 : 0);
  const float* Bf = (const float*)Bv;
  const float* bias = biasAll + (ZM ? z*512 : 0);
  void* outv = (ZM && z) ? out2 : out1;
  const float scale = (ZM && z) ? scale2 : scale1;
  const int arow=t>>2, akc=(t&3)*8;
  const int cl=t>>3, s8=(t&7)*8;

  uint4 ra; float4 raf0, raf1;
  uint4 rb0, rb1; float4 rbf0, rbf1, rbf2, rbf3;

  auto loadAB=[&](int kk){
    if(AMODE==0){
      const u16* A=(const u16*)Aptr;
      ra=*(const uint4*)(A+(size_t)(m0+arow)*512+kk+akc);
    }else if(AMODE==1){
      const float* A=(const float*)Aptr;
      raf0=*(const float4*)(A+(size_t)(kk+cl)*4096+m0+s8);
      raf1=*(const float4*)(A+(size_t)(kk+cl)*4096+m0+s8+4);
    }else{
      const float* A=(const float*)Aptr;
      raf0=*(const float4*)(A+(size_t)(m0+arow)*512+kk+akc);
      raf1=*(const float4*)(A+(size_t)(m0+arow)*512+kk+akc+4);
    }
    if(BMODE==2){
      rbf0=*(const float4*)(Bf+(size_t)(kk+cl)*4096+n0+s8);
      rbf1=*(const float4*)(Bf+(size_t)(kk+cl)*4096+n0+s8+4);
      rbf2=*(const float4*)(Bf+(size_t)(kk+cl)*4096+n0+64+s8);
      rbf3=*(const float4*)(Bf+(size_t)(kk+cl)*4096+n0+64+s8+4);
    }else if(BMODE==1){
      rb0=*(const uint4*)(Bu+((size_t)((kk>>6)*4096+n0+arow))*64+(kk&63)+akc);
      rb1=*(const uint4*)(Bu+((size_t)((kk>>6)*4096+n0+64+arow))*64+(kk&63)+akc);
    }else{
      rb0=*(const uint4*)(Bu+(size_t)(n0+arow)*512+kk+akc);
      rb1=*(const uint4*)(Bu+(size_t)(n0+64+arow)*512+kk+akc);
    }
  };
  auto writeAB=[&](int b){
    if(AMODE==0){ stlds(&As[b][arow*18+(akc>>1)],ra); }
    else if(AMODE==1){
      float f[8]={raf0.x,raf0.y,raf0.z,raf0.w,raf1.x,raf1.y,raf1.z,raf1.w};
      u16* As16=(u16*)As[b];
      #pragma unroll
      for(int j=0;j<8;j++) As16[(s8+j)*36+cl]=f2bf(f[j]);
    }else{
      stlds(&As[b][arow*18+(akc>>1)],pack8(raf0,raf1));
    }
    if(BMODE==2){
      u16* Bs16=(u16*)Bs[b];
      float f[8]={rbf0.x,rbf0.y,rbf0.z,rbf0.w,rbf1.x,rbf1.y,rbf1.z,rbf1.w};
      float g[8]={rbf2.x,rbf2.y,rbf2.z,rbf2.w,rbf3.x,rbf3.y,rbf3.z,rbf3.w};
      #pragma unroll
      for(int j=0;j<8;j++){
        Bs16[(s8+j)*36+cl]=f2bf(f[j]);
        Bs16[(64+s8+j)*36+cl]=f2bf(g[j]);
      }
    }else{
      stlds(&Bs[b][arow*18+(akc>>1)],rb0);
      stlds(&Bs[b][(64+arow)*18+(akc>>1)],rb1);
    }
  };

  f32x4 acc[2][4];
  #pragma unroll
  for(int i=0;i<2;i++)
    #pragma unroll
    for(int j=0;j<4;j++){ acc[i][j].x=0.f; acc[i][j].y=0.f; acc[i][j].z=0.f; acc[i][j].w=0.f; }

  loadAB(0); writeAB(0);
  __syncthreads();
  for(int kk=0;kk<512;kk+=32){
    const int cur=(kk>>5)&1;
    const bool nxt = (kk+32)<512;
    if(nxt) loadAB(kk+32);
    u32x4 af[2], bfr[4];
    #pragma unroll
    for(int mt=0;mt<2;mt++) af[mt]=ldfrag(&As[cur][(wm*32+mt*16+l15)*18+quad*4]);
    #pragma unroll
    for(int nt=0;nt<4;nt++) bfr[nt]=ldfrag(&Bs[cur][(wn*64+nt*16+l15)*18+quad*4]);
    #pragma unroll
    for(int mt=0;mt<2;mt++)
      #pragma unroll
      for(int nt=0;nt<4;nt++) acc[mt][nt]=mfma16(af[mt],bfr[nt],acc[mt][nt]);
    if(nxt){
      __syncthreads();
      writeAB(1-cur);
      __syncthreads();
    }
  }
  #pragma unroll
  for(int mt=0;mt<2;mt++)
    #pragma unroll
    for(int nt=0;nt<4;nt++){
      const int n = n0 + wn*64 + nt*16 + l15;
      if(SMODE==0){
        u16* out=(u16*)outv;
        const float bn = bias[n];
        const size_t base = ((size_t)((n>>6)*4096))*64 + (size_t)(n&63);
        #pragma unroll
        for(int r=0;r<4;r++){
          int m = m0 + wm*32 + mt*16 + quad*4 + r;
          out[base + (size_t)m*64] = f2bf((acc[mt][nt][r]+bn)*scale);
        }
      } else if(SMODE==1){
        u16* out=(u16*)outv;
        #pragma unroll
        for(int r=0;r<4;r++){
          int m = m0 + wm*32 + mt*16 + quad*4 + r;
          out[(size_t)m*4096+n] = f2bf(acc[mt][nt][r] + bias[m]);
        }
      } else {
        float* out=(float*)outv;
        #pragma unroll
        for(int r=0;r<4;r++){
          int m = m0 + wm*32 + mt*16 + quad*4 + r;
          out[(size_t)m*4096+n] = acc[mt][nt][r] + bias[m] + residf[(size_t)m*4096+n];
        }
      }
    }
}

// ---------------- flash attention, no-max exp2 softmax, dbuf K/V --------------
// Q,K head layout [h][s][64]; V plain [h*64+cc][s]; O head layout [h][s][64].
// Q pre-scaled by 0.125*log2e. Scores bounded (|s|<~20) -> exp2 w/o max shift
// is exact softmax; per-lane partial row-sums reduced once at the end.
__global__ __launch_bounds__(256) void k_attn(const u16* __restrict__ Qh,const u16* __restrict__ Kh,
                                              const u16* __restrict__ Vp,u16* __restrict__ Oh){
  __shared__ __align__(16) u32 Qs[64*34];
  __shared__ __align__(16) u32 Ks[2][64*34];
  __shared__ __align__(16) u32 Vs[2][64*34];
  __shared__ __align__(16) u32 Ps[4][16*34];
  const int t=threadIdx.x, lane=t&63, w=t>>6, quad=lane>>4, l15=lane&15;
  const int h=blockIdx.y, s0=blockIdx.x*64;
  const int srow=t>>2, sc=(t&3)*16;
  // Q tile + tile0 K/V staging under one barrier
  { const u16* p = Qh + ((size_t)(h*4096+s0+srow))*64 + sc;
    stlds(&Qs[srow*34+(sc>>1)],   *(const uint4*)p);
    stlds(&Qs[srow*34+(sc>>1)+4], *(const uint4*)(p+8));
    const u16* kp = Kh + ((size_t)(h*4096+srow))*64 + sc;
    stlds(&Ks[0][srow*34+(sc>>1)],   *(const uint4*)kp);
    stlds(&Ks[0][srow*34+(sc>>1)+4], *(const uint4*)(kp+8));
    const u16* vp = Vp + (size_t)(h*64+srow)*4096 + sc;
    stlds(&Vs[0][srow*34+(sc>>1)],   *(const uint4*)vp);
    stlds(&Vs[0][srow*34+(sc>>1)+4], *(const uint4*)(vp+8)); }
  __syncthreads();
  u32x4 qf[2];
  #pragma unroll
  for(int ks=0;ks<2;ks++) qf[ks]=ldfrag(&Qs[(w*16+l15)*34+ks*16+quad*4]);
  float lrun[4]; f32x4 oacc[4];
  #pragma unroll
  for(int r=0;r<4;r++) lrun[r]=0.f;
  #pragma unroll
  for(int nt=0;nt<4;nt++){ oacc[nt].x=0.f; oacc[nt].y=0.f; oacc[nt].z=0.f; oacc[nt].w=0.f; }

  for(int t0=0;t0<4096;t0+=64){
    const int cur=(t0>>6)&1;
    const bool nxt = (t0+64)<4096;
    uint4 pk0,pk1,pv0,pv1;
    if(nxt){
      const u16* kp = Kh + ((size_t)(h*4096+t0+64+srow))*64 + sc;
      pk0=*(const uint4*)kp; pk1=*(const uint4*)(kp+8);
      const u16* vp = Vp + (size_t)(h*64+srow)*4096 + t0+64 + sc;
      pv0=*(const uint4*)vp; pv1=*(const uint4*)(vp+8);
    }
    // QK^T
    f32x4 sv[4];
    #pragma unroll
    for(int nt=0;nt<4;nt++){
      f32x4 zz; zz.x=0.f; zz.y=0.f; zz.z=0.f; zz.w=0.f;
      u32x4 k0=ldfrag(&Ks[cur][(nt*16+l15)*34+quad*4]);
      u32x4 k1=ldfrag(&Ks[cur][(nt*16+l15)*34+16+quad*4]);
      zz=mfma16(qf[0],k0,zz);
      sv[nt]=mfma16(qf[1],k1,zz);
    }
    // exp2, stash P (bf16), accumulate per-lane partial row sums
    u16* pw_=(u16*)Ps[w];
    #pragma unroll
    for(int nt=0;nt<4;nt++)
      #pragma unroll
      for(int r=0;r<4;r++){
        float p=exp2f(sv[nt][r]);
        sv[nt][r]=p;
        pw_[(quad*4+r)*68 + nt*16 + l15]=f2bf(p);
      }
    #pragma unroll
    for(int r=0;r<4;r++) lrun[r]+=(sv[0][r]+sv[1][r])+(sv[2][r]+sv[3][r]);
    // P·V
    #pragma unroll
    for(int ks=0;ks<2;ks++){
      u32x4 pf=ldfrag(&Ps[w][l15*34+ks*16+quad*4]);
      #pragma unroll
      for(int nt=0;nt<4;nt++){
        u32x4 vf=ldfrag(&Vs[cur][(nt*16+l15)*34+ks*16+quad*4]);
        oacc[nt]=mfma16(pf,vf,oacc[nt]);
      }
    }
    if(nxt){
      __syncthreads();
      stlds(&Ks[1-cur][srow*34+(sc>>1)],   pk0);
      stlds(&Ks[1-cur][srow*34+(sc>>1)+4], pk1);
      stlds(&Vs[1-cur][srow*34+(sc>>1)],   pv0);
      stlds(&Vs[1-cur][srow*34+(sc>>1)+4], pv1);
      __syncthreads();
    }
  }
  #pragma unroll
  for(int r=0;r<4;r++){
    float l=lrun[r];
    #pragma unroll
    for(int m=1;m<16;m<<=1) l+=__shfl_xor(l,m,64);
    float inv=1.f/l;
    #pragma unroll
    for(int nt=0;nt<4;nt++) oacc[nt][r]*=inv;
  }
  #pragma unroll
  for(int nt=0;nt<4;nt++)
    #pragma unroll
    for(int r=0;r<4;r++)
      Oh[((size_t)(h*4096+s0+w*16+quad*4+r))*64 + nt*16 + l15]=f2bf(oacc[nt][r]);
}

// ------------------------------- launcher -------------------------------------
extern "C" void kernel_launch(void* const* d_in, const int* in_sizes, int n_in,
                              void* d_out, int out_size, void* d_ws, size_t ws_size,
                              hipStream_t stream){
  (void)in_sizes; (void)n_in; (void)out_size; (void)ws_size;
  const float* x  =(const float*)d_in[0];
  const float* ctx=(const float*)d_in[1];
  const float* nw =(const float*)d_in[2];
  const float* nb =(const float*)d_in[3];
  const float* ncw=(const float*)d_in[4];
  const float* ncb=(const float*)d_in[5];
  const float* qw =(const float*)d_in[6];
  const float* qb =(const float*)d_in[7];
  const float* kvw=(const float*)d_in[8];
  const float* kvb=(const float*)d_in[9];
  const float* pw =(const float*)d_in[10];
  const float* pb =(const float*)d_in[11];
  float* out=(float*)d_out;
  char* ws=(char*)d_ws;
  float* stats  =(float*)ws;                 // [0, 128)
  float* biasAll=(float*)(ws+256);           // 2048 f32 (q,k,v,proj)
  u16* Wall=(u16*)(ws+16384);                // 1536x512 bf16
  u16* Qh  =(u16*)(ws+1589248);              // [8][4096][64] bf16
  u16* Kh  =(u16*)(ws+5783552);
  u16* Vp  =(u16*)(ws+9977856);              // [512][4096]
  u16* Oh  =(u16*)(ws+14172160);             // ends 18366464

  hipMemsetAsync(stats,0,128,stream);
  k_stats<<<dim3(128),dim3(256),0,stream>>>(x,ctx,stats);
  k_prep<<<dim3(512),dim3(256),0,stream>>>(qw,qb,kvw,kvb,nw,nb,ncw,ncb,pb,stats,Wall,biasAll);
  // Q (z=0, from x) and K (z=1, from ctx) in one launch
  k_gemm<1,0,0,1><<<dim3(4,64,2),dim3(256),0,stream>>>(x, ctx, Wall, biasAll, nullptr, Qh, Kh, 0.125f*LOG2E, 1.f);
  // V: V[co][s] = Wv' * ctx
  k_gemm<0,2,1,0><<<dim3(32,8),dim3(256),0,stream>>>(Wall+(size_t)1024*512, nullptr, ctx, biasAll+1024, nullptr, Vp, nullptr, 1.f, 1.f);
  k_attn<<<dim3(64,8),dim3(256),0,stream>>>(Qh,Kh,Vp,Oh);
  // proj + residual (fp32 out)
  k_gemm<2,1,2,0><<<dim3(32,8),dim3(256),0,stream>>>(pw, nullptr, Oh, biasAll+1536, x, out, nullptr, 1.f, 1.f);
}

// Round 6
// 207.097 us; speedup vs baseline: 1.5962x; 1.1606x over previous
//
#include <hip/hip_runtime.h>

typedef unsigned short u16;
typedef unsigned int u32;
typedef float f32x4 __attribute__((ext_vector_type(4)));
typedef __bf16 bf16x8 __attribute__((ext_vector_type(8)));
typedef u32 u32x4 __attribute__((ext_vector_type(4)));

#define LOG2E 1.44269504088896340736f

static __device__ __forceinline__ u16 f2bf(float f){ u32 u=__builtin_bit_cast(u32,f); u32 r=u+0x7fffu+((u>>16)&1u); return (u16)(r>>16); }
static __device__ __forceinline__ u32 pk2(float a,float b){ return (u32)f2bf(a)|((u32)f2bf(b)<<16); }
static __device__ __forceinline__ float fexp2(float x){
#if __has_builtin(__builtin_amdgcn_exp2f)
  return __builtin_amdgcn_exp2f(x);
#else
  float r; asm volatile("v_exp_f32 %0, %1" : "=v"(r) : "v"(x)); return r;
#endif
}
static __device__ __forceinline__ f32x4 mfma16(u32x4 a,u32x4 b,f32x4 c){
  return __builtin_amdgcn_mfma_f32_16x16x32_bf16(__builtin_bit_cast(bf16x8,a),__builtin_bit_cast(bf16x8,b),c,0,0,0);
}
static __device__ __forceinline__ u32x4 ldfrag(const u32* p){
  uint2 a=*(const uint2*)p; uint2 b=*(const uint2*)(p+2);
  u32x4 r; r.x=a.x; r.y=a.y; r.z=b.x; r.w=b.y; return r;
}
static __device__ __forceinline__ void stlds(u32* d, uint4 v){
  *(uint2*)d = make_uint2(v.x,v.y); *(uint2*)(d+2) = make_uint2(v.z,v.w);
}
static __device__ __forceinline__ uint4 pack8(float4 a,float4 b){
  uint4 o; o.x=pk2(a.x,a.y); o.y=pk2(a.z,a.w); o.z=pk2(b.x,b.y); o.w=pk2(b.z,b.w); return o;
}

// ---------------- group-norm statistics: per-group sum / sumsq ----------------
__global__ __launch_bounds__(256) void k_stats(const float* __restrict__ x, const float* __restrict__ c,
                                               float* __restrict__ stats){
  const int g=blockIdx.x>>3, slice=blockIdx.x&7;
  const float* src=(g<8?x:c)+(size_t)(g&7)*262144+(size_t)slice*32768;
  const float4* p=(const float4*)src;
  const int t=threadIdx.x;
  float s1=0.f,s2=0.f;
  for(int i=0;i<32;i++){
    float4 v=p[t+i*256];
    s1+=v.x+v.y+v.z+v.w;
    s2+=v.x*v.x+v.y*v.y+v.z*v.z+v.w*v.w;
  }
  #pragma unroll
  for(int m=1;m<64;m<<=1){ s1+=__shfl_xor(s1,m,64); s2+=__shfl_xor(s2,m,64); }
  __shared__ float r1[4],r2[4];
  const int lane=t&63,w=t>>6;
  if(lane==0){ r1[w]=s1; r2[w]=s2; }
  __syncthreads();
  if(t==0){
    atomicAdd(&stats[2*g],   r1[0]+r1[1]+r1[2]+r1[3]);
    atomicAdd(&stats[2*g+1], r2[0]+r2[1]+r2[2]+r2[3]);
  }
}

// ------------- fold group-norm affine into GEMM weights + biases --------------
__global__ __launch_bounds__(256) void k_prep(const float* __restrict__ qw,const float* __restrict__ qb,
    const float* __restrict__ kvw,const float* __restrict__ kvb,
    const float* __restrict__ nw,const float* __restrict__ nb,
    const float* __restrict__ ncw,const float* __restrict__ ncb,
    const float* __restrict__ pb,const float* __restrict__ stats,
    u16* __restrict__ Wall,float* __restrict__ biasAll){
  const int lane=threadIdx.x&63, w=threadIdx.x>>6;
  const int r=blockIdx.x*4+w;
  if(r>=1536){ if(lane==0) biasAll[r]=pb[r-1536]; return; }
  const bool isq = r<512;
  const float* Wsrc = isq ? qw+(size_t)r*512 : kvw+(size_t)(r-512)*512;
  const float* anw = isq ? nw : ncw;
  const float* anb = isq ? nb : ncb;
  const int gbase = isq ? 0 : 8;
  const float bin = isq ? qb[r] : kvb[r-512];
  const int ci0=lane*8;
  float4 wa=*(const float4*)(Wsrc+ci0);
  float4 wb=*(const float4*)(Wsrc+ci0+4);
  float wf[8]={wa.x,wa.y,wa.z,wa.w,wb.x,wb.y,wb.z,wb.w};
  float bp=0.f; u16 hb[8];
  #pragma unroll
  for(int j=0;j<8;j++){
    int ci=ci0+j;
    int g=gbase+(ci>>6);
    float mean=stats[2*g]*(1.f/262144.f);
    float var =stats[2*g+1]*(1.f/262144.f)-mean*mean;
    float rstd=rsqrtf(var+1e-5f);
    float alv=anw[ci]*rstd;
    float bev=anb[ci]-mean*alv;
    bp+=wf[j]*bev;
    hb[j]=f2bf(wf[j]*alv);
  }
  uint4 ov;
  ov.x=(u32)hb[0]|((u32)hb[1]<<16);
  ov.y=(u32)hb[2]|((u32)hb[3]<<16);
  ov.z=(u32)hb[4]|((u32)hb[5]<<16);
  ov.w=(u32)hb[6]|((u32)hb[7]<<16);
  *(uint4*)(Wall+(size_t)r*512+ci0)=ov;
  #pragma unroll
  for(int m=1;m<64;m<<=1) bp+=__shfl_xor(bp,m,64);
  if(lane==0) biasAll[r]=bin+bp;
}

// ---------------- BT-form GEMM: C[m][n] = sum_k A[m][k]*B[n][k], K=512 --------
// BM=64, BN=128, BK=32; double-buffered LDS (unrolled x2, single barrier/phase).
template<int AMODE,int BMODE,int SMODE,int ZM>
__global__ __launch_bounds__(256) void k_gemm(const void* __restrict__ Av,const void* __restrict__ Av2,
    const void* __restrict__ Bv,const float* __restrict__ biasAll,const float* __restrict__ residf,
    void* __restrict__ out1,void* __restrict__ out2,float scale1,float scale2){
  __shared__ __align__(16) u32 As[2][64*18];
  __shared__ __align__(16) u32 Bs[2][128*18];
  const int t=threadIdx.x, lane=t&63, w=t>>6;
  const int wm=w&1, wn=w>>1, quad=lane>>4, l15=lane&15;
  const int m0=blockIdx.y*64, n0=blockIdx.x*128;
  const int z = ZM ? blockIdx.z : 0;
  const void* Aptr = (ZM && z) ? Av2 : Av;
  const u16* Bu = (const u16*)Bv + (BMODE==0 ? (size_t)z*512*512 : 0);
  const float* Bf = (const float*)Bv;
  const float* bias = biasAll + (ZM ? z*512 : 0);
  void* outv = (ZM && z) ? out2 : out1;
  const float scale = (ZM && z) ? scale2 : scale1;
  const int arow=t>>2, akc=(t&3)*8;
  const int cl=t>>3, s8=(t&7)*8;

  uint4 ra; float4 raf0, raf1;
  uint4 rb0, rb1; float4 rbf0, rbf1, rbf2, rbf3;

  auto loadAB=[&](int kk){
    if(AMODE==0){
      const u16* A=(const u16*)Aptr;
      ra=*(const uint4*)(A+(size_t)(m0+arow)*512+kk+akc);
    }else if(AMODE==1){
      const float* A=(const float*)Aptr;
      raf0=*(const float4*)(A+(size_t)(kk+cl)*4096+m0+s8);
      raf1=*(const float4*)(A+(size_t)(kk+cl)*4096+m0+s8+4);
    }else{
      const float* A=(const float*)Aptr;
      raf0=*(const float4*)(A+(size_t)(m0+arow)*512+kk+akc);
      raf1=*(const float4*)(A+(size_t)(m0+arow)*512+kk+akc+4);
    }
    if(BMODE==2){
      rbf0=*(const float4*)(Bf+(size_t)(kk+cl)*4096+n0+s8);
      rbf1=*(const float4*)(Bf+(size_t)(kk+cl)*4096+n0+s8+4);
      rbf2=*(const float4*)(Bf+(size_t)(kk+cl)*4096+n0+64+s8);
      rbf3=*(const float4*)(Bf+(size_t)(kk+cl)*4096+n0+64+s8+4);
    }else if(BMODE==1){
      rb0=*(const uint4*)(Bu+((size_t)((kk>>6)*4096+n0+arow))*64+(kk&63)+akc);
      rb1=*(const uint4*)(Bu+((size_t)((kk>>6)*4096+n0+64+arow))*64+(kk&63)+akc);
    }else{
      rb0=*(const uint4*)(Bu+(size_t)(n0+arow)*512+kk+akc);
      rb1=*(const uint4*)(Bu+(size_t)(n0+64+arow)*512+kk+akc);
    }
  };
  auto writeAB=[&](u32* Asb,u32* Bsb){
    if(AMODE==0){ stlds(&Asb[arow*18+(akc>>1)],ra); }
    else if(AMODE==1){
      float f[8]={raf0.x,raf0.y,raf0.z,raf0.w,raf1.x,raf1.y,raf1.z,raf1.w};
      u16* As16=(u16*)Asb;
      #pragma unroll
      for(int j=0;j<8;j++) As16[(s8+j)*36+cl]=f2bf(f[j]);
    }else{
      stlds(&Asb[arow*18+(akc>>1)],pack8(raf0,raf1));
    }
    if(BMODE==2){
      u16* Bs16=(u16*)Bsb;
      float f[8]={rbf0.x,rbf0.y,rbf0.z,rbf0.w,rbf1.x,rbf1.y,rbf1.z,rbf1.w};
      float g[8]={rbf2.x,rbf2.y,rbf2.z,rbf2.w,rbf3.x,rbf3.y,rbf3.z,rbf3.w};
      #pragma unroll
      for(int j=0;j<8;j++){
        Bs16[(s8+j)*36+cl]=f2bf(f[j]);
        Bs16[(64+s8+j)*36+cl]=f2bf(g[j]);
      }
    }else{
      stlds(&Bsb[arow*18+(akc>>1)],rb0);
      stlds(&Bsb[(64+arow)*18+(akc>>1)],rb1);
    }
  };

  f32x4 acc[2][4];
  #pragma unroll
  for(int i=0;i<2;i++)
    #pragma unroll
    for(int j=0;j<4;j++){ acc[i][j].x=0.f; acc[i][j].y=0.f; acc[i][j].z=0.f; acc[i][j].w=0.f; }

  auto compute=[&](const u32* Asb,const u32* Bsb){
    const u32* Ab=Asb+(wm*32+l15)*18+quad*4;
    const u32* Bb=Bsb+(wn*64+l15)*18+quad*4;
    u32x4 af[2], bfr[4];
    #pragma unroll
    for(int mt=0;mt<2;mt++) af[mt]=ldfrag(Ab+mt*288);
    #pragma unroll
    for(int nt=0;nt<4;nt++) bfr[nt]=ldfrag(Bb+nt*288);
    #pragma unroll
    for(int mt=0;mt<2;mt++)
      #pragma unroll
      for(int nt=0;nt<4;nt++) acc[mt][nt]=mfma16(af[mt],bfr[nt],acc[mt][nt]);
  };

  loadAB(0); writeAB(As[0],Bs[0]);
  __syncthreads();
  for(int kk=0;kk<512;kk+=64){
    loadAB(kk+32);                      // kk+32 <= 480, always valid
    compute(As[0],Bs[0]);
    writeAB(As[1],Bs[1]);
    __syncthreads();
    const bool n2=(kk+64)<512;
    if(n2) loadAB(kk+64);
    compute(As[1],Bs[1]);
    if(n2){ writeAB(As[0],Bs[0]); __syncthreads(); }
  }
  #pragma unroll
  for(int mt=0;mt<2;mt++)
    #pragma unroll
    for(int nt=0;nt<4;nt++){
      const int n = n0 + wn*64 + nt*16 + l15;
      if(SMODE==0){
        u16* out=(u16*)outv;
        const float bn = bias[n];
        const size_t base = ((size_t)((n>>6)*4096))*64 + (size_t)(n&63);
        #pragma unroll
        for(int r=0;r<4;r++){
          int m = m0 + wm*32 + mt*16 + quad*4 + r;
          out[base + (size_t)m*64] = f2bf((acc[mt][nt][r]+bn)*scale);
        }
      } else if(SMODE==1){
        u16* out=(u16*)outv;
        #pragma unroll
        for(int r=0;r<4;r++){
          int m = m0 + wm*32 + mt*16 + quad*4 + r;
          out[(size_t)m*4096+n] = f2bf(acc[mt][nt][r] + bias[m]);
        }
      } else {
        float* out=(float*)outv;
        #pragma unroll
        for(int r=0;r<4;r++){
          int m = m0 + wm*32 + mt*16 + quad*4 + r;
          out[(size_t)m*4096+n] = acc[mt][nt][r] + bias[m] + residf[(size_t)m*4096+n];
        }
      }
    }
}

// ---------------- flash attention, no-max exp2 softmax, dbuf K/V --------------
// Q,K head layout [h][s][64]; V plain [h*64+cc][s]; O head layout [h][s][64].
// Q pre-scaled by 0.125*log2e. Unrolled x2 (compile-time buffers), raw v_exp_f32,
// RTZ bf16 for the P stash, one barrier per 64-key tile.
__global__ __launch_bounds__(256) void k_attn(const u16* __restrict__ Qh,const u16* __restrict__ Kh,
                                              const u16* __restrict__ Vp,u16* __restrict__ Oh){
  __shared__ __align__(16) u32 Qs[64*34];
  __shared__ __align__(16) u32 Ks[2][64*34];
  __shared__ __align__(16) u32 Vs[2][64*34];
  __shared__ __align__(16) u32 Ps[4][16*34];
  const int t=threadIdx.x, lane=t&63, w=t>>6, quad=lane>>4, l15=lane&15;
  const int h=blockIdx.y, s0=blockIdx.x*64;
  const int srow=t>>2, sc=(t&3)*16;
  const u16* Kg = Kh + ((size_t)(h*4096+srow))*64 + sc;       // + key*64
  const u16* Vg = Vp + (size_t)(h*64+srow)*4096 + sc;          // + key
  // Q tile + tile0 K/V staging under one barrier
  { const u16* p = Qh + ((size_t)(h*4096+s0+srow))*64 + sc;
    stlds(&Qs[srow*34+(sc>>1)],   *(const uint4*)p);
    stlds(&Qs[srow*34+(sc>>1)+4], *(const uint4*)(p+8));
    stlds(&Ks[0][srow*34+(sc>>1)],   *(const uint4*)Kg);
    stlds(&Ks[0][srow*34+(sc>>1)+4], *(const uint4*)(Kg+8));
    stlds(&Vs[0][srow*34+(sc>>1)],   *(const uint4*)Vg);
    stlds(&Vs[0][srow*34+(sc>>1)+4], *(const uint4*)(Vg+8)); }
  __syncthreads();
  u32x4 qf[2];
  #pragma unroll
  for(int ks=0;ks<2;ks++) qf[ks]=ldfrag(&Qs[(w*16+l15)*34+ks*16+quad*4]);
  float lrun[4]; f32x4 oacc[4];
  #pragma unroll
  for(int r=0;r<4;r++) lrun[r]=0.f;
  #pragma unroll
  for(int nt=0;nt<4;nt++){ oacc[nt].x=0.f; oacc[nt].y=0.f; oacc[nt].z=0.f; oacc[nt].w=0.f; }

  u16* Pw=(u16*)Ps[w]+(quad*4)*68+l15;
  const u32* Pb=Ps[w]+l15*34+quad*4;

  auto halfstep=[&](const u32* Kc,const u32* Vc,u32* Kn,u32* Vn,int t0,bool pf){
    uint4 pk0,pk1,pv0,pv1;
    if(pf){
      const u16* kp=Kg+(size_t)(t0+64)*64;
      pk0=*(const uint4*)kp; pk1=*(const uint4*)(kp+8);
      const u16* vp=Vg+(t0+64);
      pv0=*(const uint4*)vp; pv1=*(const uint4*)(vp+8);
    }
    // QK^T
    f32x4 sv[4];
    const u32* Kb=Kc+l15*34+quad*4;
    #pragma unroll
    for(int nt=0;nt<4;nt++){
      f32x4 zz; zz.x=0.f; zz.y=0.f; zz.z=0.f; zz.w=0.f;
      u32x4 k0=ldfrag(Kb+nt*544);
      u32x4 k1=ldfrag(Kb+nt*544+16);
      zz=mfma16(qf[0],k0,zz);
      sv[nt]=mfma16(qf[1],k1,zz);
    }
    // exp2 (raw v_exp_f32), RTZ bf16 stash, per-lane partial row sums
    #pragma unroll
    for(int nt=0;nt<4;nt++)
      #pragma unroll
      for(int r=0;r<4;r++){
        float p=fexp2(sv[nt][r]);
        sv[nt][r]=p;
        Pw[r*68+nt*16]=(u16)(__builtin_bit_cast(u32,p)>>16);
      }
    #pragma unroll
    for(int r=0;r<4;r++) lrun[r]+=(sv[0][r]+sv[1][r])+(sv[2][r]+sv[3][r]);
    // P·V
    const u32* Vb=Vc+l15*34+quad*4;
    #pragma unroll
    for(int ks=0;ks<2;ks++){
      u32x4 pfr=ldfrag(Pb+ks*16);
      #pragma unroll
      for(int nt=0;nt<4;nt++){
        u32x4 vf=ldfrag(Vb+nt*544+ks*16);
        oacc[nt]=mfma16(pfr,vf,oacc[nt]);
      }
    }
    if(pf){
      u32* Knw=Kn+srow*34+(sc>>1);
      u32* Vnw=Vn+srow*34+(sc>>1);
      stlds(Knw,pk0); stlds(Knw+4,pk1);
      stlds(Vnw,pv0); stlds(Vnw+4,pv1);
      __syncthreads();
    }
  };

  for(int t0=0;t0<4096;t0+=128){
    halfstep(Ks[0],Vs[0],Ks[1],Vs[1],t0,true);
    halfstep(Ks[1],Vs[1],Ks[0],Vs[0],t0+64,(t0+128)<4096);
  }

  #pragma unroll
  for(int r=0;r<4;r++){
    float l=lrun[r];
    #pragma unroll
    for(int m=1;m<16;m<<=1) l+=__shfl_xor(l,m,64);
    float inv=1.f/l;
    #pragma unroll
    for(int nt=0;nt<4;nt++) oacc[nt][r]*=inv;
  }
  #pragma unroll
  for(int nt=0;nt<4;nt++)
    #pragma unroll
    for(int r=0;r<4;r++)
      Oh[((size_t)(h*4096+s0+w*16+quad*4+r))*64 + nt*16 + l15]=f2bf(oacc[nt][r]);
}

// ------------------------------- launcher -------------------------------------
extern "C" void kernel_launch(void* const* d_in, const int* in_sizes, int n_in,
                              void* d_out, int out_size, void* d_ws, size_t ws_size,
                              hipStream_t stream){
  (void)in_sizes; (void)n_in; (void)out_size; (void)ws_size;
  const float* x  =(const float*)d_in[0];
  const float* ctx=(const float*)d_in[1];
  const float* nw =(const float*)d_in[2];
  const float* nb =(const float*)d_in[3];
  const float* ncw=(const float*)d_in[4];
  const float* ncb=(const float*)d_in[5];
  const float* qw =(const float*)d_in[6];
  const float* qb =(const float*)d_in[7];
  const float* kvw=(const float*)d_in[8];
  const float* kvb=(const float*)d_in[9];
  const float* pw =(const float*)d_in[10];
  const float* pb =(const float*)d_in[11];
  float* out=(float*)d_out;
  char* ws=(char*)d_ws;
  float* stats  =(float*)ws;                 // [0, 128)
  float* biasAll=(float*)(ws+256);           // 2048 f32 (q,k,v,proj)
  u16* Wall=(u16*)(ws+16384);                // 1536x512 bf16
  u16* Qh  =(u16*)(ws+1589248);              // [8][4096][64] bf16
  u16* Kh  =(u16*)(ws+5783552);
  u16* Vp  =(u16*)(ws+9977856);              // [512][4096]
  u16* Oh  =(u16*)(ws+14172160);             // ends 18366464

  (void)hipMemsetAsync(stats,0,128,stream);
  k_stats<<<dim3(128),dim3(256),0,stream>>>(x,ctx,stats);
  k_prep<<<dim3(512),dim3(256),0,stream>>>(qw,qb,kvw,kvb,nw,nb,ncw,ncb,pb,stats,Wall,biasAll);
  // Q (z=0, from x) and K (z=1, from ctx) in one launch
  k_gemm<1,0,0,1><<<dim3(4,64,2),dim3(256),0,stream>>>(x, ctx, Wall, biasAll, nullptr, Qh, Kh, 0.125f*LOG2E, 1.f);
  // V: V[co][s] = Wv' * ctx
  k_gemm<0,2,1,0><<<dim3(32,8),dim3(256),0,stream>>>(Wall+(size_t)1024*512, nullptr, ctx, biasAll+1024, nullptr, Vp, nullptr, 1.f, 1.f);
  k_attn<<<dim3(64,8),dim3(256),0,stream>>>(Qh,Kh,Vp,Oh);
  // proj + residual (fp32 out)
  k_gemm<2,1,2,0><<<dim3(32,8),dim3(256),0,stream>>>(pw, nullptr, Oh, biasAll+1536, x, out, nullptr, 1.f, 1.f);
}

// Round 7
// 189.668 us; speedup vs baseline: 1.7429x; 1.0919x over previous
//
#include <hip/hip_runtime.h>

typedef unsigned short u16;
typedef unsigned int u32;
typedef float f32x4 __attribute__((ext_vector_type(4)));
typedef __bf16 bf16x8 __attribute__((ext_vector_type(8)));
typedef u32 u32x4 __attribute__((ext_vector_type(4)));
typedef u32 u32x2 __attribute__((ext_vector_type(2)));
typedef short s16x4 __attribute__((ext_vector_type(4)));

#define LOG2E 1.44269504088896340736f

static __device__ __forceinline__ u16 f2bf(float f){ u32 u=__builtin_bit_cast(u32,f); u32 r=u+0x7fffu+((u>>16)&1u); return (u16)(r>>16); }
static __device__ __forceinline__ u32 pk2(float a,float b){ return (u32)f2bf(a)|((u32)f2bf(b)<<16); }
static __device__ __forceinline__ float fexp2(float x){
#if __has_builtin(__builtin_amdgcn_exp2f)
  return __builtin_amdgcn_exp2f(x);
#else
  float r; asm volatile("v_exp_f32 %0, %1" : "=v"(r) : "v"(x)); return r;
#endif
}
static __device__ __forceinline__ f32x4 mfma16(u32x4 a,u32x4 b,f32x4 c){
  return __builtin_amdgcn_mfma_f32_16x16x32_bf16(__builtin_bit_cast(bf16x8,a),__builtin_bit_cast(bf16x8,b),c,0,0,0);
}
#if __has_builtin(__builtin_amdgcn_mfma_f32_16x16x16bf16_1k)
static __device__ __forceinline__ f32x4 mfma1k(s16x4 a,s16x4 b,f32x4 c){
  return __builtin_amdgcn_mfma_f32_16x16x16bf16_1k(a,b,c,0,0,0);
}
#else
static __device__ __forceinline__ f32x4 mfma1k(s16x4 a,s16x4 b,f32x4 c){
  f32x4 d; asm("v_mfma_f32_16x16x16_bf16 %0, %1, %2, %3":"=v"(d):"v"(a),"v"(b),"v"(c)); return d;
}
#endif
static __device__ __forceinline__ u32x4 ldfrag(const u32* p){
  uint2 a=*(const uint2*)p; uint2 b=*(const uint2*)(p+2);
  u32x4 r; r.x=a.x; r.y=a.y; r.z=b.x; r.w=b.y; return r;
}
static __device__ __forceinline__ s16x4 ld8(const u32* p){
  return __builtin_bit_cast(s16x4, *(const u32x2*)p);
}
static __device__ __forceinline__ void stlds(u32* d, uint4 v){
  *(uint2*)d = make_uint2(v.x,v.y); *(uint2*)(d+2) = make_uint2(v.z,v.w);
}
static __device__ __forceinline__ uint4 pack8(float4 a,float4 b){
  uint4 o; o.x=pk2(a.x,a.y); o.y=pk2(a.z,a.w); o.z=pk2(b.x,b.y); o.w=pk2(b.z,b.w); return o;
}

// ---------------- group-norm statistics: per-group sum / sumsq ----------------
__global__ __launch_bounds__(256) void k_stats(const float* __restrict__ x, const float* __restrict__ c,
                                               float* __restrict__ stats){
  const int g=blockIdx.x>>3, slice=blockIdx.x&7;
  const float* src=(g<8?x:c)+(size_t)(g&7)*262144+(size_t)slice*32768;
  const float4* p=(const float4*)src;
  const int t=threadIdx.x;
  float s1=0.f,s2=0.f;
  for(int i=0;i<32;i++){
    float4 v=p[t+i*256];
    s1+=v.x+v.y+v.z+v.w;
    s2+=v.x*v.x+v.y*v.y+v.z*v.z+v.w*v.w;
  }
  #pragma unroll
  for(int m=1;m<64;m<<=1){ s1+=__shfl_xor(s1,m,64); s2+=__shfl_xor(s2,m,64); }
  __shared__ float r1[4],r2[4];
  const int lane=t&63,w=t>>6;
  if(lane==0){ r1[w]=s1; r2[w]=s2; }
  __syncthreads();
  if(t==0){
    atomicAdd(&stats[2*g],   r1[0]+r1[1]+r1[2]+r1[3]);
    atomicAdd(&stats[2*g+1], r2[0]+r2[1]+r2[2]+r2[3]);
  }
}

// ------------- fold group-norm affine into GEMM weights + biases --------------
__global__ __launch_bounds__(256) void k_prep(const float* __restrict__ qw,const float* __restrict__ qb,
    const float* __restrict__ kvw,const float* __restrict__ kvb,
    const float* __restrict__ nw,const float* __restrict__ nb,
    const float* __restrict__ ncw,const float* __restrict__ ncb,
    const float* __restrict__ pb,const float* __restrict__ stats,
    u16* __restrict__ Wall,float* __restrict__ biasAll){
  const int lane=threadIdx.x&63, w=threadIdx.x>>6;
  const int r=blockIdx.x*4+w;
  if(r>=1536){ if(lane==0) biasAll[r]=pb[r-1536]; return; }
  const bool isq = r<512;
  const float* Wsrc = isq ? qw+(size_t)r*512 : kvw+(size_t)(r-512)*512;
  const float* anw = isq ? nw : ncw;
  const float* anb = isq ? nb : ncb;
  const int gbase = isq ? 0 : 8;
  const float bin = isq ? qb[r] : kvb[r-512];
  const int ci0=lane*8;
  float4 wa=*(const float4*)(Wsrc+ci0);
  float4 wb=*(const float4*)(Wsrc+ci0+4);
  float wf[8]={wa.x,wa.y,wa.z,wa.w,wb.x,wb.y,wb.z,wb.w};
  float bp=0.f; u16 hb[8];
  #pragma unroll
  for(int j=0;j<8;j++){
    int ci=ci0+j;
    int g=gbase+(ci>>6);
    float mean=stats[2*g]*(1.f/262144.f);
    float var =stats[2*g+1]*(1.f/262144.f)-mean*mean;
    float rstd=rsqrtf(var+1e-5f);
    float alv=anw[ci]*rstd;
    float bev=anb[ci]-mean*alv;
    bp+=wf[j]*bev;
    hb[j]=f2bf(wf[j]*alv);
  }
  uint4 ov;
  ov.x=(u32)hb[0]|((u32)hb[1]<<16);
  ov.y=(u32)hb[2]|((u32)hb[3]<<16);
  ov.z=(u32)hb[4]|((u32)hb[5]<<16);
  ov.w=(u32)hb[6]|((u32)hb[7]<<16);
  *(uint4*)(Wall+(size_t)r*512+ci0)=ov;
  #pragma unroll
  for(int m=1;m<64;m<<=1) bp+=__shfl_xor(bp,m,64);
  if(lane==0) biasAll[r]=bin+bp;
}

// ---------------- BT-form GEMM: C[m][n] = sum_k A[m][k]*B[n][k], K=512 --------
// BM=64, BN=128, BK=32; double-buffered LDS (unrolled x2, single barrier/phase).
template<int AMODE,int BMODE,int SMODE,int ZM>
__global__ __launch_bounds__(256) void k_gemm(const void* __restrict__ Av,const void* __restrict__ Av2,
    const void* __restrict__ Bv,const float* __restrict__ biasAll,const float* __restrict__ residf,
    void* __restrict__ out1,void* __restrict__ out2,float scale1,float scale2){
  __shared__ __align__(16) u32 As[2][64*18];
  __shared__ __align__(16) u32 Bs[2][128*18];
  const int t=threadIdx.x, lane=t&63, w=t>>6;
  const int wm=w&1, wn=w>>1, quad=lane>>4, l15=lane&15;
  const int m0=blockIdx.y*64, n0=blockIdx.x*128;
  const int z = ZM ? blockIdx.z : 0;
  const void* Aptr = (ZM && z) ? Av2 : Av;
  const u16* Bu = (const u16*)Bv + (BMODE==0 ? (size_t)z*512*512 : 0);
  const float* Bf = (const float*)Bv;
  const float* bias = biasAll + (ZM ? z*512 : 0);
  void* outv = (ZM && z) ? out2 : out1;
  const float scale = (ZM && z) ? scale2 : scale1;
  const int arow=t>>2, akc=(t&3)*8;
  const int cl=t>>3, s8=(t&7)*8;

  uint4 ra; float4 raf0, raf1;
  uint4 rb0, rb1; float4 rbf0, rbf1, rbf2, rbf3;

  auto loadAB=[&](int kk){
    if(AMODE==0){
      const u16* A=(const u16*)Aptr;
      ra=*(const uint4*)(A+(size_t)(m0+arow)*512+kk+akc);
    }else if(AMODE==1){
      const float* A=(const float*)Aptr;
      raf0=*(const float4*)(A+(size_t)(kk+cl)*4096+m0+s8);
      raf1=*(const float4*)(A+(size_t)(kk+cl)*4096+m0+s8+4);
    }else{
      const float* A=(const float*)Aptr;
      raf0=*(const float4*)(A+(size_t)(m0+arow)*512+kk+akc);
      raf1=*(const float4*)(A+(size_t)(m0+arow)*512+kk+akc+4);
    }
    if(BMODE==2){
      rbf0=*(const float4*)(Bf+(size_t)(kk+cl)*4096+n0+s8);
      rbf1=*(const float4*)(Bf+(size_t)(kk+cl)*4096+n0+s8+4);
      rbf2=*(const float4*)(Bf+(size_t)(kk+cl)*4096+n0+64+s8);
      rbf3=*(const float4*)(Bf+(size_t)(kk+cl)*4096+n0+64+s8+4);
    }else if(BMODE==1){
      rb0=*(const uint4*)(Bu+((size_t)((kk>>6)*4096+n0+arow))*64+(kk&63)+akc);
      rb1=*(const uint4*)(Bu+((size_t)((kk>>6)*4096+n0+64+arow))*64+(kk&63)+akc);
    }else{
      rb0=*(const uint4*)(Bu+(size_t)(n0+arow)*512+kk+akc);
      rb1=*(const uint4*)(Bu+(size_t)(n0+64+arow)*512+kk+akc);
    }
  };
  auto writeAB=[&](u32* Asb,u32* Bsb){
    if(AMODE==0){ stlds(&Asb[arow*18+(akc>>1)],ra); }
    else if(AMODE==1){
      float f[8]={raf0.x,raf0.y,raf0.z,raf0.w,raf1.x,raf1.y,raf1.z,raf1.w};
      u16* As16=(u16*)Asb;
      #pragma unroll
      for(int j=0;j<8;j++) As16[(s8+j)*36+cl]=f2bf(f[j]);
    }else{
      stlds(&Asb[arow*18+(akc>>1)],pack8(raf0,raf1));
    }
    if(BMODE==2){
      u16* Bs16=(u16*)Bsb;
      float f[8]={rbf0.x,rbf0.y,rbf0.z,rbf0.w,rbf1.x,rbf1.y,rbf1.z,rbf1.w};
      float g[8]={rbf2.x,rbf2.y,rbf2.z,rbf2.w,rbf3.x,rbf3.y,rbf3.z,rbf3.w};
      #pragma unroll
      for(int j=0;j<8;j++){
        Bs16[(s8+j)*36+cl]=f2bf(f[j]);
        Bs16[(64+s8+j)*36+cl]=f2bf(g[j]);
      }
    }else{
      stlds(&Bsb[arow*18+(akc>>1)],rb0);
      stlds(&Bsb[(64+arow)*18+(akc>>1)],rb1);
    }
  };

  f32x4 acc[2][4];
  #pragma unroll
  for(int i=0;i<2;i++)
    #pragma unroll
    for(int j=0;j<4;j++){ acc[i][j].x=0.f; acc[i][j].y=0.f; acc[i][j].z=0.f; acc[i][j].w=0.f; }

  auto compute=[&](const u32* Asb,const u32* Bsb){
    const u32* Ab=Asb+(wm*32+l15)*18+quad*4;
    const u32* Bb=Bsb+(wn*64+l15)*18+quad*4;
    u32x4 af[2], bfr[4];
    #pragma unroll
    for(int mt=0;mt<2;mt++) af[mt]=ldfrag(Ab+mt*288);
    #pragma unroll
    for(int nt=0;nt<4;nt++) bfr[nt]=ldfrag(Bb+nt*288);
    #pragma unroll
    for(int mt=0;mt<2;mt++)
      #pragma unroll
      for(int nt=0;nt<4;nt++) acc[mt][nt]=mfma16(af[mt],bfr[nt],acc[mt][nt]);
  };

  loadAB(0); writeAB(As[0],Bs[0]);
  __syncthreads();
  for(int kk=0;kk<512;kk+=64){
    loadAB(kk+32);
    compute(As[0],Bs[0]);
    writeAB(As[1],Bs[1]);
    __syncthreads();
    const bool n2=(kk+64)<512;
    if(n2) loadAB(kk+64);
    compute(As[1],Bs[1]);
    if(n2){ writeAB(As[0],Bs[0]); __syncthreads(); }
  }
  #pragma unroll
  for(int mt=0;mt<2;mt++)
    #pragma unroll
    for(int nt=0;nt<4;nt++){
      const int n = n0 + wn*64 + nt*16 + l15;
      if(SMODE==0){
        u16* out=(u16*)outv;
        const float bn = bias[n];
        const size_t base = ((size_t)((n>>6)*4096))*64 + (size_t)(n&63);
        #pragma unroll
        for(int r=0;r<4;r++){
          int m = m0 + wm*32 + mt*16 + quad*4 + r;
          out[base + (size_t)m*64] = f2bf((acc[mt][nt][r]+bn)*scale);
        }
      } else if(SMODE==1){
        u16* out=(u16*)outv;
        #pragma unroll
        for(int r=0;r<4;r++){
          int m = m0 + wm*32 + mt*16 + quad*4 + r;
          out[(size_t)m*4096+n] = f2bf(acc[mt][nt][r] + bias[m]);
        }
      } else {
        float* out=(float*)outv;
        #pragma unroll
        for(int r=0;r<4;r++){
          int m = m0 + wm*32 + mt*16 + quad*4 + r;
          out[(size_t)m*4096+n] = acc[mt][nt][r] + bias[m] + residf[(size_t)m*4096+n];
        }
      }
    }
}

// -------- flash attention: S^T via swapped-operand 16x16x16 MFMA --------------
// Key identity: mfma_16x16x16 A-frag layout (m=lane&15, k=quad*4+j) == C/D
// layout (col=lane&15, row=quad*4+reg). Computing S^T = K·Q^T makes the exp2'd
// score registers directly usable as the A-operand of P·V — no P LDS round-trip.
// 512 threads: waves 0-3 keys [0,2048), waves 4-7 keys [2048,4096) (split-K,
// exact since no-max softmax is linear); merge via LDS at the end.
// Q,K head layout [h][s][64]; V plain [h*64+c][s]; O head layout [h][s][64].
__global__ __launch_bounds__(512,4) void k_attn(const u16* __restrict__ Qh,const u16* __restrict__ Kh,
                                              const u16* __restrict__ Vp,u16* __restrict__ Oh){
  __shared__ __align__(16) u32 KS[2][2][64*34];   // [half][buf][key][c]
  __shared__ __align__(16) u32 VS[2][2][64*34];   // [half][buf][c][key]
  const int t=threadIdx.x, lane=t&63, w=t>>6, quad=lane>>4, l15=lane&15;
  const int half=w>>2, wq=w&3;
  const int h=blockIdx.y, s0=blockIdx.x*64;
  const int tt=t&255, srow=tt>>2, sc=(tt&3)*16;
  const u16* Kg = Kh + ((size_t)(h*4096 + half*2048 + srow))*64 + sc;   // +key*64
  const u16* Vg = Vp + (size_t)(h*64+srow)*4096 + half*2048 + sc;       // +key
  // Q fragments direct from global (B-operand: n=query=l15, k=c=quad*4+j)
  const u16* Qg = Qh + ((size_t)(h*4096+s0+wq*16+l15))*64;
  s16x4 qf[4];
  #pragma unroll
  for(int kc=0;kc<4;kc++) qf[kc]=ld8((const u32*)(Qg + kc*16 + quad*4));

  uint4 pk0,pk1,pv0,pv1;
  auto loadKV=[&](int t0l){
    const u16* kp=Kg+(size_t)t0l*64;
    pk0=*(const uint4*)kp; pk1=*(const uint4*)(kp+8);
    const u16* vp=Vg+t0l;
    pv0=*(const uint4*)vp; pv1=*(const uint4*)(vp+8);
  };
  auto writeKV=[&](u32* Kb,u32* Vb){
    u32* kw=Kb+srow*34+(sc>>1);
    stlds(kw,pk0); stlds(kw+4,pk1);
    u32* vw=Vb+srow*34+(sc>>1);
    stlds(vw,pv0); stlds(vw+4,pv1);
  };

  float lrun=0.f; f32x4 oacc[4];
  #pragma unroll
  for(int cn=0;cn<4;cn++){ oacc[cn].x=0.f; oacc[cn].y=0.f; oacc[cn].z=0.f; oacc[cn].w=0.f; }

  auto tilestep=[&](const u32* Kb,const u32* Vb){
    // QK^T -> S^T[key][q]: A=K (m=key), B=Q (n=query), chain 4 over channels
    f32x4 sv[4];
    #pragma unroll
    for(int nt=0;nt<4;nt++){
      const u32* kb=Kb+(nt*16+l15)*34+quad*2;
      f32x4 a; a.x=0.f; a.y=0.f; a.z=0.f; a.w=0.f;
      #pragma unroll
      for(int kc=0;kc<4;kc++) a=mfma1k(ld8(kb+kc*8),qf[kc],a);
      sv[nt]=a;
    }
    // exp2 (no max shift; scores bounded), pack RTZ to A-frag, partial row sum
    s16x4 pfr[4];
    #pragma unroll
    for(int nt=0;nt<4;nt++){
      float p0=fexp2(sv[nt].x),p1=fexp2(sv[nt].y),p2=fexp2(sv[nt].z),p3=fexp2(sv[nt].w);
      lrun+=(p0+p1)+(p2+p3);
      u32x2 pp;
      pp.x=(__builtin_bit_cast(u32,p0)>>16)|(__builtin_bit_cast(u32,p1)&0xffff0000u);
      pp.y=(__builtin_bit_cast(u32,p2)>>16)|(__builtin_bit_cast(u32,p3)&0xffff0000u);
      pfr[nt]=__builtin_bit_cast(s16x4,pp);
    }
    // P·V: A=P^T regs (m=q), B=V (n=c), chain 4 over key-16 blocks
    #pragma unroll
    for(int cn=0;cn<4;cn++){
      const u32* vb=Vb+(cn*16+l15)*34+quad*2;
      f32x4 a=oacc[cn];
      #pragma unroll
      for(int nt=0;nt<4;nt++) a=mfma1k(pfr[nt],ld8(vb+nt*8),a);
      oacc[cn]=a;
    }
  };

  loadKV(0); writeKV(KS[half][0],VS[half][0]);
  __syncthreads();
  for(int t0=0;t0<2048;t0+=128){
    loadKV(t0+64);
    tilestep(KS[half][0],VS[half][0]);
    writeKV(KS[half][1],VS[half][1]);
    __syncthreads();
    const bool more=(t0+128)<2048;
    if(more) loadKV(t0+128);
    tilestep(KS[half][1],VS[half][1]);
    if(more){ writeKV(KS[half][0],VS[half][0]); __syncthreads(); }
  }
  // merge halves: waves 4-7 dump unnormalized state into half1's K region
  __syncthreads();
  float* cb=(float*)KS[1];                    // 4352 u32 = 4 waves*64 lanes*17 f32
  const int cbi=(wq*64+lane)*17;
  if(half==1){
    #pragma unroll
    for(int cn=0;cn<4;cn++)
      #pragma unroll
      for(int r=0;r<4;r++) cb[cbi+cn*4+r]=oacc[cn][r];
    cb[cbi+16]=lrun;
  }
  __syncthreads();
  if(half==0){
    #pragma unroll
    for(int cn=0;cn<4;cn++)
      #pragma unroll
      for(int r=0;r<4;r++) oacc[cn][r]+=cb[cbi+cn*4+r];
    lrun+=cb[cbi+16];
    float l=lrun;
    l+=__shfl_xor(l,16,64);
    l+=__shfl_xor(l,32,64);                   // all lanes: l for query l15
    #pragma unroll
    for(int r=0;r<4;r++){
      float inv=1.f/__shfl(l,quad*4+r,64);    // l for query quad*4+r
      #pragma unroll
      for(int cn=0;cn<4;cn++)
        Oh[((size_t)(h*4096+s0+wq*16+quad*4+r))*64 + cn*16 + l15]=f2bf(oacc[cn][r]*inv);
    }
  }
}

// ------------------------------- launcher -------------------------------------
extern "C" void kernel_launch(void* const* d_in, const int* in_sizes, int n_in,
                              void* d_out, int out_size, void* d_ws, size_t ws_size,
                              hipStream_t stream){
  (void)in_sizes; (void)n_in; (void)out_size; (void)ws_size;
  const float* x  =(const float*)d_in[0];
  const float* ctx=(const float*)d_in[1];
  const float* nw =(const float*)d_in[2];
  const float* nb =(const float*)d_in[3];
  const float* ncw=(const float*)d_in[4];
  const float* ncb=(const float*)d_in[5];
  const float* qw =(const float*)d_in[6];
  const float* qb =(const float*)d_in[7];
  const float* kvw=(const float*)d_in[8];
  const float* kvb=(const float*)d_in[9];
  const float* pw =(const float*)d_in[10];
  const float* pb =(const float*)d_in[11];
  float* out=(float*)d_out;
  char* ws=(char*)d_ws;
  float* stats  =(float*)ws;                 // [0, 128)
  float* biasAll=(float*)(ws+256);           // 2048 f32 (q,k,v,proj)
  u16* Wall=(u16*)(ws+16384);                // 1536x512 bf16
  u16* Qh  =(u16*)(ws+1589248);              // [8][4096][64] bf16
  u16* Kh  =(u16*)(ws+5783552);
  u16* Vp  =(u16*)(ws+9977856);              // [512][4096]
  u16* Oh  =(u16*)(ws+14172160);             // ends 18366464

  (void)hipMemsetAsync(stats,0,128,stream);
  k_stats<<<dim3(128),dim3(256),0,stream>>>(x,ctx,stats);
  k_prep<<<dim3(512),dim3(256),0,stream>>>(qw,qb,kvw,kvb,nw,nb,ncw,ncb,pb,stats,Wall,biasAll);
  // Q (z=0, from x) and K (z=1, from ctx) in one launch
  k_gemm<1,0,0,1><<<dim3(4,64,2),dim3(256),0,stream>>>(x, ctx, Wall, biasAll, nullptr, Qh, Kh, 0.125f*LOG2E, 1.f);
  // V: V[co][s] = Wv' * ctx
  k_gemm<0,2,1,0><<<dim3(32,8),dim3(256),0,stream>>>(Wall+(size_t)1024*512, nullptr, ctx, biasAll+1024, nullptr, Vp, nullptr, 1.f, 1.f);
  k_attn<<<dim3(64,8),dim3(512),0,stream>>>(Qh,Kh,Vp,Oh);
  // proj + residual (fp32 out)
  k_gemm<2,1,2,0><<<dim3(32,8),dim3(256),0,stream>>>(pw, nullptr, Oh, biasAll+1536, x, out, nullptr, 1.f, 1.f);
}

// Round 8
// 176.428 us; speedup vs baseline: 1.8737x; 1.0750x over previous
//
#include <hip/hip_runtime.h>

typedef unsigned short u16;
typedef unsigned int u32;
typedef float f32x4 __attribute__((ext_vector_type(4)));
typedef __bf16 bf16x8 __attribute__((ext_vector_type(8)));
typedef u32 u32x4 __attribute__((ext_vector_type(4)));
typedef u32 u32x2 __attribute__((ext_vector_type(2)));
typedef short s16x4 __attribute__((ext_vector_type(4)));

#define LOG2E 1.44269504088896340736f

static __device__ __forceinline__ u16 f2bf(float f){ u32 u=__builtin_bit_cast(u32,f); u32 r=u+0x7fffu+((u>>16)&1u); return (u16)(r>>16); }
static __device__ __forceinline__ u32 pk2(float a,float b){ return (u32)f2bf(a)|((u32)f2bf(b)<<16); }
static __device__ __forceinline__ float fexp2(float x){
#if __has_builtin(__builtin_amdgcn_exp2f)
  return __builtin_amdgcn_exp2f(x);
#else
  float r; asm volatile("v_exp_f32 %0, %1" : "=v"(r) : "v"(x)); return r;
#endif
}
static __device__ __forceinline__ f32x4 mfma16(u32x4 a,u32x4 b,f32x4 c){
  return __builtin_amdgcn_mfma_f32_16x16x32_bf16(__builtin_bit_cast(bf16x8,a),__builtin_bit_cast(bf16x8,b),c,0,0,0);
}
#if __has_builtin(__builtin_amdgcn_mfma_f32_16x16x16bf16_1k)
static __device__ __forceinline__ f32x4 mfma1k(s16x4 a,s16x4 b,f32x4 c){
  return __builtin_amdgcn_mfma_f32_16x16x16bf16_1k(a,b,c,0,0,0);
}
#else
static __device__ __forceinline__ f32x4 mfma1k(s16x4 a,s16x4 b,f32x4 c){
  f32x4 d; asm("v_mfma_f32_16x16x16_bf16 %0, %1, %2, %3":"=v"(d):"v"(a),"v"(b),"v"(c)); return d;
}
#endif
static __device__ __forceinline__ u32x4 ldfrag(const u32* p){
  uint2 a=*(const uint2*)p; uint2 b=*(const uint2*)(p+2);
  u32x4 r; r.x=a.x; r.y=a.y; r.z=b.x; r.w=b.y; return r;
}
static __device__ __forceinline__ s16x4 ld8(const u32* p){
  return __builtin_bit_cast(s16x4, *(const u32x2*)p);
}
static __device__ __forceinline__ void stlds(u32* d, uint4 v){
  *(uint2*)d = make_uint2(v.x,v.y); *(uint2*)(d+2) = make_uint2(v.z,v.w);
}
static __device__ __forceinline__ uint4 pack8(float4 a,float4 b){
  uint4 o; o.x=pk2(a.x,a.y); o.y=pk2(a.z,a.w); o.z=pk2(b.x,b.y); o.w=pk2(b.z,b.w); return o;
}

// ------------- group-norm stats: per-(group,slice) partial sums ---------------
// 128 blocks: g=bid>>3 (0..15, 8..15 = ctx), slice=bid&7. No atomics, no memset.
__global__ __launch_bounds__(256) void k_stats(const float* __restrict__ x, const float* __restrict__ c,
                                               float* __restrict__ stats){
  const int g=blockIdx.x>>3, slice=blockIdx.x&7;
  const float* src=(g<8?x:c)+(size_t)(g&7)*262144+(size_t)slice*32768;
  const float4* p=(const float4*)src;
  const int t=threadIdx.x;
  float s1=0.f,s2=0.f;
  for(int i=0;i<32;i++){
    float4 v=p[t+i*256];
    s1+=v.x+v.y+v.z+v.w;
    s2+=v.x*v.x+v.y*v.y+v.z*v.z+v.w*v.w;
  }
  #pragma unroll
  for(int m=1;m<64;m<<=1){ s1+=__shfl_xor(s1,m,64); s2+=__shfl_xor(s2,m,64); }
  __shared__ float r1[4],r2[4];
  const int lane=t&63,w=t>>6;
  if(lane==0){ r1[w]=s1; r2[w]=s2; }
  __syncthreads();
  if(t==0){
    stats[blockIdx.x*2  ]=r1[0]+r1[1]+r1[2]+r1[3];
    stats[blockIdx.x*2+1]=r2[0]+r2[1]+r2[2]+r2[3];
  }
}

// -------------------- fused Q/K/V GEMM (one dispatch, 768 blocks) -------------
// blocks [0,256): Q = norm(x)·qw^T    -> Qh head layout, bias qb, *qscale
// blocks [256,512): K = norm(ctx)·kvw[0:512]^T -> Kh head layout, bias kvb[0:512]
// blocks [512,768): V = kvw[512:1024]·norm(ctx) -> Vp [co][s], bias kvb[512+co]
// GroupNorm applied to the ACTIVATION during LDS staging (al*v+bt per element);
// weights are staged raw fp32->bf16. BM=64,BN=128,BK=32, dbuf, 1 barrier/phase.
__global__ __launch_bounds__(256) void k_qkv(const float* __restrict__ x,const float* __restrict__ ctx,
    const float* __restrict__ qw,const float* __restrict__ qb,
    const float* __restrict__ kvw,const float* __restrict__ kvb,
    const float* __restrict__ nw,const float* __restrict__ nb,
    const float* __restrict__ ncw,const float* __restrict__ ncb,
    const float* __restrict__ stats,
    u16* __restrict__ Qh,u16* __restrict__ Kh,u16* __restrict__ Vp,float qscale){
  __shared__ __align__(16) u32 As[2][64*18];
  __shared__ __align__(16) u32 Bs[2][128*18];
  __shared__ float AB[1024];   // al[0:512], bt[512:1024]
  __shared__ float mr[16];     // mean,rstd per group (8 groups of this operand)
  const int bid=blockIdx.x, t=threadIdx.x, lane=t&63, w=t>>6;
  const int wm=w&1, wn=w>>1, quad=lane>>4, l15=lane&15;
  const bool isV = bid>=512;
  const int z = isV ? 1 : (bid>>8);           // 0: x-norm (Q), 1: ctx-norm (K,V)
  int m0,n0;
  if(isV){ int v=bid-512; n0=(v&31)*128; m0=(v>>5)*64; }
  else   { int r=bid&255; n0=(r&3)*128; m0=(r>>2)*64; }
  // ---- prologue: group stats -> per-channel alpha/beta table ----
  const float* anw = z ? ncw : nw;
  const float* anb = z ? ncb : nb;
  if(t<8){
    const int gb = z ? 8 : 0;
    float s1=0.f,s2=0.f;
    #pragma unroll
    for(int s=0;s<8;s++){ s1+=stats[((gb+t)*8+s)*2]; s2+=stats[((gb+t)*8+s)*2+1]; }
    float mean=s1*(1.f/262144.f);
    float var =s2*(1.f/262144.f)-mean*mean;
    mr[t*2]=mean; mr[t*2+1]=rsqrtf(var+1e-5f);
  }
  __syncthreads();
  #pragma unroll
  for(int i=0;i<2;i++){
    int ci=t+i*256, g=ci>>6;
    float al=anw[ci]*mr[g*2+1];
    AB[ci]=al; AB[512+ci]=anb[ci]-mr[g*2]*al;
  }
  __syncthreads();

  const int arow=t>>2, akc=(t&3)*8;
  const int cl=t>>3, s8=(t&7)*8;
  const float* act = z ? ctx : x;
  const float* W   = z ? kvw : qw;
  float4 ta0,ta1,tb0,tb1,tb2,tb3;
  int kpend=0;

  auto loadAB=[&](int kk){
    kpend=kk;
    if(!isV){
      ta0=*(const float4*)(act+(size_t)(kk+cl)*4096+m0+s8);
      ta1=*(const float4*)(act+(size_t)(kk+cl)*4096+m0+s8+4);
      tb0=*(const float4*)(W+(size_t)(n0+arow)*512+kk+akc);
      tb1=*(const float4*)(W+(size_t)(n0+arow)*512+kk+akc+4);
      tb2=*(const float4*)(W+(size_t)(n0+64+arow)*512+kk+akc);
      tb3=*(const float4*)(W+(size_t)(n0+64+arow)*512+kk+akc+4);
    }else{
      ta0=*(const float4*)(kvw+(size_t)(512+m0+arow)*512+kk+akc);
      ta1=*(const float4*)(kvw+(size_t)(512+m0+arow)*512+kk+akc+4);
      tb0=*(const float4*)(ctx+(size_t)(kk+cl)*4096+n0+s8);
      tb1=*(const float4*)(ctx+(size_t)(kk+cl)*4096+n0+s8+4);
      tb2=*(const float4*)(ctx+(size_t)(kk+cl)*4096+n0+64+s8);
      tb3=*(const float4*)(ctx+(size_t)(kk+cl)*4096+n0+64+s8+4);
    }
  };
  auto writeAB=[&](u32* Asb,u32* Bsb){
    if(!isV){
      const float al=AB[kpend+cl], bt=AB[512+kpend+cl];
      float f[8]={ta0.x,ta0.y,ta0.z,ta0.w,ta1.x,ta1.y,ta1.z,ta1.w};
      u16* As16=(u16*)Asb;
      #pragma unroll
      for(int j=0;j<8;j++) As16[(s8+j)*36+cl]=f2bf(al*f[j]+bt);
      stlds(&Bsb[arow*18+(akc>>1)],pack8(tb0,tb1));
      stlds(&Bsb[(64+arow)*18+(akc>>1)],pack8(tb2,tb3));
    }else{
      stlds(&Asb[arow*18+(akc>>1)],pack8(ta0,ta1));
      const float al=AB[kpend+cl], bt=AB[512+kpend+cl];
      float f[8]={tb0.x,tb0.y,tb0.z,tb0.w,tb1.x,tb1.y,tb1.z,tb1.w};
      float g[8]={tb2.x,tb2.y,tb2.z,tb2.w,tb3.x,tb3.y,tb3.z,tb3.w};
      u16* Bs16=(u16*)Bsb;
      #pragma unroll
      for(int j=0;j<8;j++){
        Bs16[(s8+j)*36+cl]=f2bf(al*f[j]+bt);
        Bs16[(64+s8+j)*36+cl]=f2bf(al*g[j]+bt);
      }
    }
  };

  f32x4 acc[2][4];
  #pragma unroll
  for(int i=0;i<2;i++)
    #pragma unroll
    for(int j=0;j<4;j++){ acc[i][j].x=0.f; acc[i][j].y=0.f; acc[i][j].z=0.f; acc[i][j].w=0.f; }

  auto compute=[&](const u32* Asb,const u32* Bsb){
    const u32* Ab=Asb+(wm*32+l15)*18+quad*4;
    const u32* Bb=Bsb+(wn*64+l15)*18+quad*4;
    u32x4 af[2], bfr[4];
    #pragma unroll
    for(int mt=0;mt<2;mt++) af[mt]=ldfrag(Ab+mt*288);
    #pragma unroll
    for(int nt=0;nt<4;nt++) bfr[nt]=ldfrag(Bb+nt*288);
    #pragma unroll
    for(int mt=0;mt<2;mt++)
      #pragma unroll
      for(int nt=0;nt<4;nt++) acc[mt][nt]=mfma16(af[mt],bfr[nt],acc[mt][nt]);
  };

  loadAB(0); writeAB(As[0],Bs[0]);
  __syncthreads();
  for(int kk=0;kk<512;kk+=64){
    loadAB(kk+32);
    compute(As[0],Bs[0]);
    writeAB(As[1],Bs[1]);
    __syncthreads();
    const bool n2=(kk+64)<512;
    if(n2) loadAB(kk+64);
    compute(As[1],Bs[1]);
    if(n2){ writeAB(As[0],Bs[0]); __syncthreads(); }
  }
  #pragma unroll
  for(int mt=0;mt<2;mt++)
    #pragma unroll
    for(int nt=0;nt<4;nt++){
      const int n = n0 + wn*64 + nt*16 + l15;
      if(!isV){
        u16* out = z ? Kh : Qh;
        const float scale = z ? 1.f : qscale;
        const float bn = (z ? kvb[n] : qb[n]);
        const size_t base = ((size_t)((n>>6)*4096))*64 + (size_t)(n&63);
        #pragma unroll
        for(int r=0;r<4;r++){
          int m = m0 + wm*32 + mt*16 + quad*4 + r;
          out[base + (size_t)m*64] = f2bf((acc[mt][nt][r]+bn)*scale);
        }
      } else {
        #pragma unroll
        for(int r=0;r<4;r++){
          int m = m0 + wm*32 + mt*16 + quad*4 + r;
          Vp[(size_t)m*4096+n] = f2bf(acc[mt][nt][r] + kvb[512+m]);
        }
      }
    }
}

// ---------------- proj GEMM: out[c][s] = pw·O + pb + x (fp32 out) -------------
__global__ __launch_bounds__(256) void k_proj(const float* __restrict__ A,const u16* __restrict__ B,
    const float* __restrict__ bias,const float* __restrict__ residf,float* __restrict__ out){
  __shared__ __align__(16) u32 As[2][64*18];
  __shared__ __align__(16) u32 Bs[2][128*18];
  const int t=threadIdx.x, lane=t&63, w=t>>6;
  const int wm=w&1, wn=w>>1, quad=lane>>4, l15=lane&15;
  const int m0=blockIdx.y*64, n0=blockIdx.x*128;
  const int arow=t>>2, akc=(t&3)*8;
  float4 ra0,ra1; uint4 rb0,rb1;
  auto loadAB=[&](int kk){
    ra0=*(const float4*)(A+(size_t)(m0+arow)*512+kk+akc);
    ra1=*(const float4*)(A+(size_t)(m0+arow)*512+kk+akc+4);
    rb0=*(const uint4*)(B+((size_t)((kk>>6)*4096+n0+arow))*64+(kk&63)+akc);
    rb1=*(const uint4*)(B+((size_t)((kk>>6)*4096+n0+64+arow))*64+(kk&63)+akc);
  };
  auto writeAB=[&](u32* Asb,u32* Bsb){
    stlds(&Asb[arow*18+(akc>>1)],pack8(ra0,ra1));
    stlds(&Bsb[arow*18+(akc>>1)],rb0);
    stlds(&Bsb[(64+arow)*18+(akc>>1)],rb1);
  };
  f32x4 acc[2][4];
  #pragma unroll
  for(int i=0;i<2;i++)
    #pragma unroll
    for(int j=0;j<4;j++){ acc[i][j].x=0.f; acc[i][j].y=0.f; acc[i][j].z=0.f; acc[i][j].w=0.f; }
  auto compute=[&](const u32* Asb,const u32* Bsb){
    const u32* Ab=Asb+(wm*32+l15)*18+quad*4;
    const u32* Bb=Bsb+(wn*64+l15)*18+quad*4;
    u32x4 af[2], bfr[4];
    #pragma unroll
    for(int mt=0;mt<2;mt++) af[mt]=ldfrag(Ab+mt*288);
    #pragma unroll
    for(int nt=0;nt<4;nt++) bfr[nt]=ldfrag(Bb+nt*288);
    #pragma unroll
    for(int mt=0;mt<2;mt++)
      #pragma unroll
      for(int nt=0;nt<4;nt++) acc[mt][nt]=mfma16(af[mt],bfr[nt],acc[mt][nt]);
  };
  loadAB(0); writeAB(As[0],Bs[0]);
  __syncthreads();
  for(int kk=0;kk<512;kk+=64){
    loadAB(kk+32);
    compute(As[0],Bs[0]);
    writeAB(As[1],Bs[1]);
    __syncthreads();
    const bool n2=(kk+64)<512;
    if(n2) loadAB(kk+64);
    compute(As[1],Bs[1]);
    if(n2){ writeAB(As[0],Bs[0]); __syncthreads(); }
  }
  #pragma unroll
  for(int mt=0;mt<2;mt++)
    #pragma unroll
    for(int nt=0;nt<4;nt++){
      const int n = n0 + wn*64 + nt*16 + l15;
      #pragma unroll
      for(int r=0;r<4;r++){
        int m = m0 + wm*32 + mt*16 + quad*4 + r;
        out[(size_t)m*4096+n] = acc[mt][nt][r] + bias[m] + residf[(size_t)m*4096+n];
      }
    }
}

// -------- flash attention: S^T via swapped-operand MFMA, split-K 512 thr ------
// QK^T uses 16x16x32 (K-tile is the A-operand, k-contiguous in LDS; Q direct
// from global as B-operand). S^T C/D layout == 16x16x16 A-layout, so exp2'd
// scores feed P·V (K=16) straight from registers. No-max exp2 softmax (scores
// bounded); waves 0-3 keys [0,2048), waves 4-7 [2048,4096); merge via LDS.
__global__ __launch_bounds__(512,4) void k_attn(const u16* __restrict__ Qh,const u16* __restrict__ Kh,
                                              const u16* __restrict__ Vp,u16* __restrict__ Oh){
  __shared__ __align__(16) u32 KS[2][2][64*34];   // [half][buf][key][c]
  __shared__ __align__(16) u32 VS[2][2][64*34];   // [half][buf][c][key]
  const int t=threadIdx.x, lane=t&63, w=t>>6, quad=lane>>4, l15=lane&15;
  const int half=w>>2, wq=w&3;
  const int h=blockIdx.y, s0=blockIdx.x*64;
  const int tt=t&255, srow=tt>>2, sc=(tt&3)*16;
  const u16* Kg = Kh + ((size_t)(h*4096 + half*2048 + srow))*64 + sc;
  const u16* Vg = Vp + (size_t)(h*64+srow)*4096 + half*2048 + sc;
  // Q fragments (B-operand of 16x16x32): n=query=l15, k=c=quad*8+j
  const u32* Qg = (const u32*)(Qh + ((size_t)(h*4096+s0+wq*16+l15))*64);
  u32x4 qfw[2];
  qfw[0]=ldfrag(Qg + quad*4);
  qfw[1]=ldfrag(Qg + 16 + quad*4);

  uint4 pk0,pk1,pv0,pv1;
  auto loadKV=[&](int t0l){
    const u16* kp=Kg+(size_t)t0l*64;
    pk0=*(const uint4*)kp; pk1=*(const uint4*)(kp+8);
    const u16* vp=Vg+t0l;
    pv0=*(const uint4*)vp; pv1=*(const uint4*)(vp+8);
  };
  auto writeKV=[&](u32* Kb,u32* Vb){
    u32* kw=Kb+srow*34+(sc>>1);
    stlds(kw,pk0); stlds(kw+4,pk1);
    u32* vw=Vb+srow*34+(sc>>1);
    stlds(vw,pv0); stlds(vw+4,pv1);
  };

  float lrun=0.f; f32x4 oacc[4];
  #pragma unroll
  for(int cn=0;cn<4;cn++){ oacc[cn].x=0.f; oacc[cn].y=0.f; oacc[cn].z=0.f; oacc[cn].w=0.f; }

  auto tilestep=[&](const u32* Kb,const u32* Vb){
    // S^T = K·Q^T via 16x16x32: A=K (m=key, k-contig from LDS), B=Q regs
    f32x4 sv[4];
    #pragma unroll
    for(int nt=0;nt<4;nt++){
      const u32* kb=Kb+(nt*16+l15)*34+quad*4;
      f32x4 a; a.x=0.f; a.y=0.f; a.z=0.f; a.w=0.f;
      a=mfma16(ldfrag(kb),qfw[0],a);
      a=mfma16(ldfrag(kb+16),qfw[1],a);
      sv[nt]=a;
    }
    // exp2 (no max shift), pack RTZ to 16x16x16 A-frag, partial row sums
    s16x4 pfr[4];
    #pragma unroll
    for(int nt=0;nt<4;nt++){
      float p0=fexp2(sv[nt].x),p1=fexp2(sv[nt].y),p2=fexp2(sv[nt].z),p3=fexp2(sv[nt].w);
      lrun+=(p0+p1)+(p2+p3);
      u32x2 pp;
      pp.x=(__builtin_bit_cast(u32,p0)>>16)|(__builtin_bit_cast(u32,p1)&0xffff0000u);
      pp.y=(__builtin_bit_cast(u32,p2)>>16)|(__builtin_bit_cast(u32,p3)&0xffff0000u);
      pfr[nt]=__builtin_bit_cast(s16x4,pp);
    }
    // P·V (16x16x16): A=P regs (m=q, k=key), B=V from LDS [c][key]
    #pragma unroll
    for(int cn=0;cn<4;cn++){
      const u32* vb=Vb+(cn*16+l15)*34+quad*2;
      f32x4 a=oacc[cn];
      #pragma unroll
      for(int nt=0;nt<4;nt++) a=mfma1k(pfr[nt],ld8(vb+nt*8),a);
      oacc[cn]=a;
    }
  };

  loadKV(0); writeKV(KS[half][0],VS[half][0]);
  __syncthreads();
  for(int t0=0;t0<2048;t0+=128){
    loadKV(t0+64);
    tilestep(KS[half][0],VS[half][0]);
    writeKV(KS[half][1],VS[half][1]);
    __syncthreads();
    const bool more=(t0+128)<2048;
    if(more) loadKV(t0+128);
    tilestep(KS[half][1],VS[half][1]);
    if(more){ writeKV(KS[half][0],VS[half][0]); __syncthreads(); }
  }
  // merge halves: waves 4-7 dump unnormalized state into half1's K region
  __syncthreads();
  float* cb=(float*)KS[1];
  const int cbi=(wq*64+lane)*17;
  if(half==1){
    #pragma unroll
    for(int cn=0;cn<4;cn++)
      #pragma unroll
      for(int r=0;r<4;r++) cb[cbi+cn*4+r]=oacc[cn][r];
    cb[cbi+16]=lrun;
  }
  __syncthreads();
  if(half==0){
    #pragma unroll
    for(int cn=0;cn<4;cn++)
      #pragma unroll
      for(int r=0;r<4;r++) oacc[cn][r]+=cb[cbi+cn*4+r];
    lrun+=cb[cbi+16];
    float l=lrun;
    l+=__shfl_xor(l,16,64);
    l+=__shfl_xor(l,32,64);
    #pragma unroll
    for(int r=0;r<4;r++){
      float inv=1.f/__shfl(l,quad*4+r,64);
      #pragma unroll
      for(int cn=0;cn<4;cn++)
        Oh[((size_t)(h*4096+s0+wq*16+quad*4+r))*64 + cn*16 + l15]=f2bf(oacc[cn][r]*inv);
    }
  }
}

// ------------------------------- launcher -------------------------------------
extern "C" void kernel_launch(void* const* d_in, const int* in_sizes, int n_in,
                              void* d_out, int out_size, void* d_ws, size_t ws_size,
                              hipStream_t stream){
  (void)in_sizes; (void)n_in; (void)out_size; (void)ws_size;
  const float* x  =(const float*)d_in[0];
  const float* ctx=(const float*)d_in[1];
  const float* nw =(const float*)d_in[2];
  const float* nb =(const float*)d_in[3];
  const float* ncw=(const float*)d_in[4];
  const float* ncb=(const float*)d_in[5];
  const float* qw =(const float*)d_in[6];
  const float* qb =(const float*)d_in[7];
  const float* kvw=(const float*)d_in[8];
  const float* kvb=(const float*)d_in[9];
  const float* pw =(const float*)d_in[10];
  const float* pb =(const float*)d_in[11];
  float* out=(float*)d_out;
  char* ws=(char*)d_ws;
  float* stats=(float*)ws;                   // 256 f32 (128 slots x 2)
  u16* Qh  =(u16*)(ws+16384);                // [8][4096][64] bf16
  u16* Kh  =(u16*)(ws+16384+4194304);
  u16* Vp  =(u16*)(ws+16384+2*4194304);      // [512][4096]
  u16* Oh  =(u16*)(ws+16384+3*4194304);      // ends ~16.8 MB

  k_stats<<<dim3(128),dim3(256),0,stream>>>(x,ctx,stats);
  k_qkv<<<dim3(768),dim3(256),0,stream>>>(x,ctx,qw,qb,kvw,kvb,nw,nb,ncw,ncb,stats,Qh,Kh,Vp,0.125f*LOG2E);
  k_attn<<<dim3(64,8),dim3(512),0,stream>>>(Qh,Kh,Vp,Oh);
  k_proj<<<dim3(32,8),dim3(256),0,stream>>>(pw,Oh,pb,x,out);
}